// Round 1
// baseline (3378.307 us; speedup 1.0000x reference)
//
#include <hip/hip_runtime.h>
#include <math.h>

#define VOCAB 50000
#define DIM 300
#define NC 256
#define KS 3
#define NCLASS 3
#define BB 128
#define L1 512
#define L2 32

// workspace layout (floats)
#define ATT_N (BB*L1*DIM)      // 19,660,800
#define ASP_N (BB*L2*DIM)      //  1,228,800
#define SY_N  (BB*L2*DIM)      //  1,228,800
#define S_N   (BB*L1*L2)       //  2,097,152
#define WBS_N (KS*DIM*NC)      //    230,400
#define WBG_N (KS*2*DIM*NC)    //    460,800
#define POOL_N (BB*NC)         //     32,768
// total ~24.94M floats ~ 99.8 MB

// Reshape conv weights to [kk][c] so lanes-over-c reads are coalesced.
__global__ void prep_weights(const float* __restrict__ ctx_w,
                             const float* __restrict__ gate_w,
                             float* __restrict__ wBs, float* __restrict__ wBg) {
    int idx = blockIdx.x * 256 + threadIdx.x;
    if (idx < WBS_N) {
        int c = idx & (NC - 1);
        int kk = idx >> 8;            // k*DIM + cin
        int k = kk / DIM, cin = kk - k * DIM;
        wBs[idx] = ctx_w[c * (DIM * KS) + cin * KS + k];
    } else if (idx < WBS_N + WBG_N) {
        int i2 = idx - WBS_N;
        int c = i2 & (NC - 1);
        int kk = i2 >> 8;             // k*2DIM + cin
        int k = kk / (2 * DIM), cin = kk - k * 2 * DIM;
        wBg[i2] = gate_w[c * (2 * DIM * KS) + cin * KS + k];
    }
}

// aspect embedding gather: one block per row
__global__ void gather_rows(const int* __restrict__ ids,
                            const float* __restrict__ wordmat,
                            float* __restrict__ out) {
    int row = blockIdx.x;
    int id = ids[row];
    const float* src = wordmat + (size_t)id * DIM;
    float* dst = out + (size_t)row * DIM;
    for (int d = threadIdx.x; d < DIM; d += blockDim.x) dst[d] = src[d];
}

// sy = relu(aspect @ W): M=4096, N=300, K=300. 32 rows per block.
__global__ __launch_bounds__(256) void gemm_relu_sy(const float* __restrict__ asp,
                                                    const float* __restrict__ Wm,
                                                    float* __restrict__ sy) {
    __shared__ float at[32 * DIM];
    int row0 = blockIdx.x * 32;
    int t = threadIdx.x;
    for (int idx = t; idx < 32 * DIM; idx += 256) at[idx] = asp[row0 * DIM + idx];
    __syncthreads();
    int lane = t & 31, ib = t >> 5;
    for (int q = 0; q < 10; ++q) {
        int e = lane + 32 * q;
        if (e >= DIM) break;
        float a0 = 0, a1 = 0, a2 = 0, a3 = 0;
        for (int d = 0; d < DIM; ++d) {
            float w = Wm[d * DIM + e];
            a0 = fmaf(at[ib * DIM + d],        w, a0);
            a1 = fmaf(at[(ib + 8) * DIM + d],  w, a1);
            a2 = fmaf(at[(ib + 16) * DIM + d], w, a2);
            a3 = fmaf(at[(ib + 24) * DIM + d], w, a3);
        }
        sy[(row0 + ib) * DIM + e]      = fmaxf(a0, 0.f);
        sy[(row0 + ib + 8) * DIM + e]  = fmaxf(a1, 0.f);
        sy[(row0 + ib + 16) * DIM + e] = fmaxf(a2, 0.f);
        sy[(row0 + ib + 24) * DIM + e] = fmaxf(a3, 0.f);
    }
}

// s[b,i,j] = relu(ctx_row_i @ W) . sy_row_j  — sx fused (each sx row used once).
__global__ __launch_bounds__(256) void s_fused(const int* __restrict__ cids,
                                               const float* __restrict__ wordmat,
                                               const float* __restrict__ Wm,
                                               const float* __restrict__ sy,
                                               float* __restrict__ s) {
    __shared__ float buf[32 * DIM];   // ctx tile, then reused for SX tile
    int b = blockIdx.y, i0 = blockIdx.x * 32, t = threadIdx.x;
    for (int idx = t; idx < 32 * DIM; idx += 256) {
        int i = idx / DIM, d = idx - i * DIM;
        int id = cids[b * L1 + i0 + i];
        buf[idx] = wordmat[(size_t)id * DIM + d];
    }
    __syncthreads();
    int lane = t & 31, ib = t >> 5;
    float r[4][10];
    #pragma unroll
    for (int q = 0; q < 10; ++q) {
        int e = lane + 32 * q;
        float a0 = 0, a1 = 0, a2 = 0, a3 = 0;
        if (e < DIM) {
            for (int d = 0; d < DIM; ++d) {
                float w = Wm[d * DIM + e];
                a0 = fmaf(buf[ib * DIM + d],        w, a0);
                a1 = fmaf(buf[(ib + 8) * DIM + d],  w, a1);
                a2 = fmaf(buf[(ib + 16) * DIM + d], w, a2);
                a3 = fmaf(buf[(ib + 24) * DIM + d], w, a3);
            }
        }
        r[0][q] = a0; r[1][q] = a1; r[2][q] = a2; r[3][q] = a3;
    }
    __syncthreads();   // all ctx reads done
    #pragma unroll
    for (int q = 0; q < 10; ++q) {
        int e = lane + 32 * q;
        if (e < DIM) {
            buf[ib * DIM + e]        = fmaxf(r[0][q], 0.f);
            buf[(ib + 8) * DIM + e]  = fmaxf(r[1][q], 0.f);
            buf[(ib + 16) * DIM + e] = fmaxf(r[2][q], 0.f);
            buf[(ib + 24) * DIM + e] = fmaxf(r[3][q], 0.f);
        }
    }
    __syncthreads();
    // phase 2: s tile = SX (32x300) @ sy[b]^T (300x32)
    int i2 = t >> 3, jb = t & 7;
    float acc[4] = {0, 0, 0, 0};
    for (int d = 0; d < DIM; ++d) {
        float v = buf[i2 * DIM + d];
        #pragma unroll
        for (int qq = 0; qq < 4; ++qq)
            acc[qq] = fmaf(v, sy[(b * L2 + jb + 8 * qq) * DIM + d], acc[qq]);
    }
    #pragma unroll
    for (int qq = 0; qq < 4; ++qq)
        s[(b * L1 + i0 + i2) * L2 + jb + 8 * qq] = acc[qq];
}

// softmax over dim=1 (L1) per (b, j), faithful to masked_softmax. In-place on s.
__global__ __launch_bounds__(256) void softmax_col(float* __restrict__ s,
                                                   const float* __restrict__ amask) {
    __shared__ float red[256];
    __shared__ float colmax[L2], colscale[L2];
    int b = blockIdx.x, t = threadIdx.x;
    int j = t & 31, ii = t >> 5;
    float* sb = s + (size_t)b * L1 * L2;
    float m = -1e30f;
    for (int i = ii; i < L1; i += 8) m = fmaxf(m, sb[i * L2 + j]);
    red[t] = m;
    __syncthreads();
    if (t < 32) {
        float mm = red[t];
        for (int p = 1; p < 8; ++p) mm = fmaxf(mm, red[p * 32 + t]);
        colmax[t] = mm;
    }
    __syncthreads();
    float cm = colmax[j];
    float sum = 0.f;
    for (int i = ii; i < L1; i += 8) sum += expf(sb[i * L2 + j] - cm);
    red[t] = sum;
    __syncthreads();
    if (t < 32) {
        float ss = 0.f;
        for (int p = 0; p < 8; ++p) ss += red[p * 32 + t];
        float mk = amask[b * L2 + t];
        colscale[t] = mk / (mk * ss + 1e-10f);   // alpha = exp*mask/(mask*sum+1e-10)
    }
    __syncthreads();
    for (int idx = t; idx < L1 * L2; idx += 256) {
        int jj = idx & 31;
        sb[idx] = expf(sb[idx] - colmax[jj]) * colscale[jj];
    }
}

// att[b,i,:] = alpha[b,i,:] @ aspect[b]
__global__ __launch_bounds__(256) void att_fused(const float* __restrict__ alpha,
                                                 const float* __restrict__ asp,
                                                 float* __restrict__ att) {
    __shared__ float aL[L2 * DIM];   // 38.4 KB
    __shared__ float pL[32 * L2];    // 4 KB
    int b = blockIdx.y, i0 = blockIdx.x * 32, t = threadIdx.x;
    for (int idx = t; idx < L2 * DIM; idx += 256) aL[idx] = asp[(size_t)b * L2 * DIM + idx];
    for (int idx = t; idx < 32 * L2; idx += 256) pL[idx] = alpha[((size_t)b * L1 + i0) * L2 + idx];
    __syncthreads();
    int d0 = t & 31, ib = t >> 5;
    #pragma unroll
    for (int p = 0; p < 4; ++p) {
        int i = ib + 8 * p;
        for (int q = 0; q < 10; ++q) {
            int d = d0 + 32 * q;
            if (d < DIM) {
                float a = 0.f;
                #pragma unroll
                for (int jj = 0; jj < L2; ++jj)
                    a = fmaf(pL[i * L2 + jj], aL[jj * DIM + d], a);
                att[((size_t)b * L1 + i0 + i) * DIM + d] = a;
            }
        }
    }
}

// Both convs + tanh/relu + product + maxpool over L1, fused.
// block = (b, 64-c tile); scans all 512 l in 16-l stages -> full max, no atomics.
__global__ __launch_bounds__(256) void conv_pool(const int* __restrict__ cids,
                                                 const float* __restrict__ wordmat,
                                                 const float* __restrict__ att,
                                                 const float* __restrict__ wBs,
                                                 const float* __restrict__ wBg,
                                                 const float* __restrict__ ctx_b,
                                                 const float* __restrict__ gate_b,
                                                 float* __restrict__ pooled) {
    __shared__ float xs[18][DIM];    // context rows (with halo), 21.6 KB
    __shared__ float xa[18][DIM];    // att rows, 21.6 KB
    __shared__ float red[256];
    int b = blockIdx.y, c0 = blockIdx.x * 64, t = threadIdx.x;
    int c = c0 + (t & 63), lsub = t >> 6;      // 4 l-slots per thread group
    float bs = ctx_b[c], bg = gate_b[c];
    float pmax = -1e30f;
    for (int lt = 0; lt < 32; ++lt) {
        __syncthreads();   // previous-stage reads complete before overwrite
        int base = lt * 16 - 1;
        for (int idx = t; idx < 18 * DIM; idx += 256) {
            int r = idx / DIM, d = idx - r * DIM;
            int lp = base + r;
            float xv = 0.f, av = 0.f;
            if (lp >= 0 && lp < L1) {
                xv = wordmat[(size_t)cids[b * L1 + lp] * DIM + d];
                av = att[((size_t)b * L1 + lp) * DIM + d];
            }
            xs[r][d] = xv; xa[r][d] = av;
        }
        __syncthreads();
        float as[4], ag[4];
        #pragma unroll
        for (int q = 0; q < 4; ++q) { as[q] = bs; ag[q] = bg; }
        const float4* xs4 = (const float4*)&xs[0][0];
        const float4* xa4 = (const float4*)&xa[0][0];
        int ls4 = lsub * 4;
        for (int c4 = 0; c4 < DIM / 4; ++c4) {
            float xvf[6][4], avf[6][4];
            #pragma unroll
            for (int r2 = 0; r2 < 6; ++r2) {
                float4 tx = xs4[(ls4 + r2) * (DIM / 4) + c4];
                float4 ta = xa4[(ls4 + r2) * (DIM / 4) + c4];
                xvf[r2][0] = tx.x; xvf[r2][1] = tx.y; xvf[r2][2] = tx.z; xvf[r2][3] = tx.w;
                avf[r2][0] = ta.x; avf[r2][1] = ta.y; avf[r2][2] = ta.z; avf[r2][3] = ta.w;
            }
            int cin0 = c4 * 4;
            #pragma unroll
            for (int k = 0; k < KS; ++k) {
                #pragma unroll
                for (int m2 = 0; m2 < 4; ++m2) {
                    int cin = cin0 + m2;
                    float wsv = wBs[(k * DIM + cin) * NC + c];
                    float w1  = wBg[(k * 2 * DIM + cin) * NC + c];
                    float w2  = wBg[(k * 2 * DIM + DIM + cin) * NC + c];
                    #pragma unroll
                    for (int q = 0; q < 4; ++q) {
                        float xf = xvf[q + k][m2];
                        float af = avf[q + k][m2];
                        as[q] = fmaf(xf, wsv, as[q]);
                        ag[q] = fmaf(xf, w1, ag[q]);
                        ag[q] = fmaf(af, w2, ag[q]);
                    }
                }
            }
        }
        #pragma unroll
        for (int q = 0; q < 4; ++q) {
            float val = tanhf(as[q]) * fmaxf(ag[q], 0.f);
            pmax = fmaxf(pmax, val);
        }
    }
    red[t] = pmax;
    __syncthreads();
    if (t < 64) {
        float m = fmaxf(fmaxf(red[t], red[t + 64]), fmaxf(red[t + 128], red[t + 192]));
        pooled[b * NC + c0 + t] = m;
    }
}

__global__ void final_linear(const float* __restrict__ pooled,
                             const float* __restrict__ lin_w,
                             const float* __restrict__ lin_b,
                             float* __restrict__ out) {
    int t = blockIdx.x * blockDim.x + threadIdx.x;
    if (t < BB * NCLASS) {
        int b = t / NCLASS, n = t - b * NCLASS;
        float a = lin_b[n];
        for (int cc = 0; cc < NC; ++cc)
            a = fmaf(pooled[b * NC + cc], lin_w[n * NC + cc], a);
        out[t] = a;
    }
}

extern "C" void kernel_launch(void* const* d_in, const int* in_sizes, int n_in,
                              void* d_out, int out_size, void* d_ws, size_t ws_size,
                              hipStream_t stream) {
    const int*   cids    = (const int*)d_in[0];
    // d_in[1] context_masks: unused by the reference computation
    const int*   aids    = (const int*)d_in[2];
    const float* amask   = (const float*)d_in[3];
    const float* wordmat = (const float*)d_in[4];
    const float* Wm      = (const float*)d_in[5];
    const float* ctx_w   = (const float*)d_in[6];
    const float* ctx_b   = (const float*)d_in[7];
    const float* gate_w  = (const float*)d_in[8];
    const float* gate_b  = (const float*)d_in[9];
    const float* lin_w   = (const float*)d_in[10];
    const float* lin_b   = (const float*)d_in[11];
    float* out = (float*)d_out;

    float* att    = (float*)d_ws;
    float* asp    = att + ATT_N;
    float* syb    = asp + ASP_N;
    float* sbuf   = syb + SY_N;
    float* wBs    = sbuf + S_N;
    float* wBg    = wBs + WBS_N;
    float* pooled = wBg + WBG_N;

    prep_weights<<<(WBS_N + WBG_N + 255) / 256, 256, 0, stream>>>(ctx_w, gate_w, wBs, wBg);
    gather_rows<<<BB * L2, 256, 0, stream>>>(aids, wordmat, asp);
    gemm_relu_sy<<<(BB * L2) / 32, 256, 0, stream>>>(asp, Wm, syb);
    s_fused<<<dim3(L1 / 32, BB), 256, 0, stream>>>(cids, wordmat, Wm, syb, sbuf);
    softmax_col<<<BB, 256, 0, stream>>>(sbuf, amask);
    att_fused<<<dim3(L1 / 32, BB), 256, 0, stream>>>(sbuf, asp, att);
    conv_pool<<<dim3(NC / 64, BB), 256, 0, stream>>>(cids, wordmat, att, wBs, wBg,
                                                     ctx_b, gate_b, pooled);
    final_linear<<<2, 256, 0, stream>>>(pooled, lin_w, lin_b, out);
}

// Round 2
// 933.561 us; speedup vs baseline: 3.6187x; 3.6187x over previous
//
#include <hip/hip_runtime.h>
#include <hip/hip_bf16.h>
#include <math.h>
#include <stdint.h>

#define VOCAB 50000
#define DIM 300
#define NC 256
#define KS 3
#define NCLASS 3
#define BB 128
#define L1 512
#define L2 32

#define XW 608          // padded cin width (19*32): [emb 300 | att 300 | 0 x8]
#define NKC 19          // K-chunks of 32 per tap
#define ROW_B (XW * 2)  // 1216 bytes per Xcat row
#define WP_HALF_B 49152 // bytes per (cb,kc) weight block: 3*16*64*16
#define WP_ELEMS (2 * NKC * 3 * 16 * 64 * 8)
#define A_LDS_B 8448    // 130 rows x 64B, padded

#define ASP_N (BB * L2 * DIM)
#define SY_N (BB * L2 * DIM)
#define S_N (BB * L1 * L2)

typedef __attribute__((ext_vector_type(8))) short bf16x8;
typedef __attribute__((ext_vector_type(4))) float f32x4;

#define GLOBAL_AS __attribute__((address_space(1)))
#define LDS_AS __attribute__((address_space(3)))

__device__ __forceinline__ void gload_lds16(const void* g, void* l) {
    // HW writes LDS at wave-uniform base + lane*16; global src is per-lane.
    __builtin_amdgcn_global_load_lds((const GLOBAL_AS void*)g, (LDS_AS void*)l, 16, 0, 0);
}

// ---------------- weight pre-pack: fragment-linear Wp[cb][kc][tap][nf][lane][8]
__global__ void prep_wp(const float* __restrict__ ctx_w,
                        const float* __restrict__ gate_w,
                        __hip_bfloat16* __restrict__ Wp) {
    int idx = blockIdx.x * 256 + threadIdx.x;
    if (idx >= WP_ELEMS) return;
    int j = idx & 7;
    int r1 = idx >> 3;
    int lane = r1 & 63;
    int r2 = r1 >> 6;
    int nf = r2 & 15;
    int r3 = r2 >> 4;
    int tap = r3 % 3;
    int r4 = r3 / 3;
    int kc = r4 % NKC;
    int cbv = r4 / NKC;
    int k = kc * 32 + ((lane >> 4) << 3) + j;     // 0..607
    int nl = (nf << 4) + (lane & 15);             // 0..255 within block cols
    int ch = cbv * 128 + (nl & 127);
    float v = 0.f;
    if ((nl >> 7) == 0) {                         // sentiment half
        if (k < 300) v = ctx_w[(ch * DIM + k) * KS + tap];
    } else {                                      // gate half
        if (k < 600) v = gate_w[(ch * 2 * DIM + k) * KS + tap];
    }
    Wp[idx] = __float2bfloat16(v);
}

// ---------------- aspect embedding gather (fp32)
__global__ void gather_rows(const int* __restrict__ ids,
                            const float* __restrict__ wordmat,
                            float* __restrict__ out) {
    int row = blockIdx.x;
    int id = ids[row];
    const float* src = wordmat + (size_t)id * DIM;
    float* dst = out + (size_t)row * DIM;
    for (int d = threadIdx.x; d < DIM; d += blockDim.x) dst[d] = src[d];
}

// ---------------- sy = relu(aspect @ W)
__global__ __launch_bounds__(256) void gemm_relu_sy(const float* __restrict__ asp,
                                                    const float* __restrict__ Wm,
                                                    float* __restrict__ sy) {
    __shared__ float at[32 * DIM];
    int row0 = blockIdx.x * 32;
    int t = threadIdx.x;
    for (int idx = t; idx < 32 * DIM; idx += 256) at[idx] = asp[row0 * DIM + idx];
    __syncthreads();
    int lane = t & 31, ib = t >> 5;
    for (int q = 0; q < 10; ++q) {
        int e = lane + 32 * q;
        if (e >= DIM) break;
        float a0 = 0, a1 = 0, a2 = 0, a3 = 0;
        for (int d = 0; d < DIM; ++d) {
            float w = Wm[d * DIM + e];
            a0 = fmaf(at[ib * DIM + d], w, a0);
            a1 = fmaf(at[(ib + 8) * DIM + d], w, a1);
            a2 = fmaf(at[(ib + 16) * DIM + d], w, a2);
            a3 = fmaf(at[(ib + 24) * DIM + d], w, a3);
        }
        sy[(row0 + ib) * DIM + e] = fmaxf(a0, 0.f);
        sy[(row0 + ib + 8) * DIM + e] = fmaxf(a1, 0.f);
        sy[(row0 + ib + 16) * DIM + e] = fmaxf(a2, 0.f);
        sy[(row0 + ib + 24) * DIM + e] = fmaxf(a3, 0.f);
    }
}

// ---------------- s[b,i,j] = relu(ctx_i @ W) . sy_j (sx fused, never stored)
__global__ __launch_bounds__(256) void s_fused(const int* __restrict__ cids,
                                               const float* __restrict__ wordmat,
                                               const float* __restrict__ Wm,
                                               const float* __restrict__ sy,
                                               float* __restrict__ s) {
    __shared__ float buf[32 * DIM];
    int b = blockIdx.y, i0 = blockIdx.x * 32, t = threadIdx.x;
    for (int idx = t; idx < 32 * DIM; idx += 256) {
        int i = idx / DIM, d = idx - i * DIM;
        int id = cids[b * L1 + i0 + i];
        buf[idx] = wordmat[(size_t)id * DIM + d];
    }
    __syncthreads();
    int lane = t & 31, ib = t >> 5;
    float r[4][10];
    #pragma unroll
    for (int q = 0; q < 10; ++q) {
        int e = lane + 32 * q;
        float a0 = 0, a1 = 0, a2 = 0, a3 = 0;
        if (e < DIM) {
            for (int d = 0; d < DIM; ++d) {
                float w = Wm[d * DIM + e];
                a0 = fmaf(buf[ib * DIM + d], w, a0);
                a1 = fmaf(buf[(ib + 8) * DIM + d], w, a1);
                a2 = fmaf(buf[(ib + 16) * DIM + d], w, a2);
                a3 = fmaf(buf[(ib + 24) * DIM + d], w, a3);
            }
        }
        r[0][q] = a0; r[1][q] = a1; r[2][q] = a2; r[3][q] = a3;
    }
    __syncthreads();
    #pragma unroll
    for (int q = 0; q < 10; ++q) {
        int e = lane + 32 * q;
        if (e < DIM) {
            buf[ib * DIM + e] = fmaxf(r[0][q], 0.f);
            buf[(ib + 8) * DIM + e] = fmaxf(r[1][q], 0.f);
            buf[(ib + 16) * DIM + e] = fmaxf(r[2][q], 0.f);
            buf[(ib + 24) * DIM + e] = fmaxf(r[3][q], 0.f);
        }
    }
    __syncthreads();
    int i2 = t >> 3, jb = t & 7;
    float acc[4] = {0, 0, 0, 0};
    for (int d = 0; d < DIM; ++d) {
        float v = buf[i2 * DIM + d];
        #pragma unroll
        for (int qq = 0; qq < 4; ++qq)
            acc[qq] = fmaf(v, sy[(b * L2 + jb + 8 * qq) * DIM + d], acc[qq]);
    }
    #pragma unroll
    for (int qq = 0; qq < 4; ++qq)
        s[(b * L1 + i0 + i2) * L2 + jb + 8 * qq] = acc[qq];
}

// ---------------- softmax over dim=1 (L1) per (b,j)
__global__ __launch_bounds__(256) void softmax_col(float* __restrict__ s,
                                                   const float* __restrict__ amask) {
    __shared__ float red[256];
    __shared__ float colmax[L2], colscale[L2];
    int b = blockIdx.x, t = threadIdx.x;
    int j = t & 31, ii = t >> 5;
    float* sb = s + (size_t)b * L1 * L2;
    float m = -1e30f;
    for (int i = ii; i < L1; i += 8) m = fmaxf(m, sb[i * L2 + j]);
    red[t] = m;
    __syncthreads();
    if (t < 32) {
        float mm = red[t];
        for (int p = 1; p < 8; ++p) mm = fmaxf(mm, red[p * 32 + t]);
        colmax[t] = mm;
    }
    __syncthreads();
    float cm = colmax[j];
    float sum = 0.f;
    for (int i = ii; i < L1; i += 8) sum += expf(sb[i * L2 + j] - cm);
    red[t] = sum;
    __syncthreads();
    if (t < 32) {
        float ss = 0.f;
        for (int p = 0; p < 8; ++p) ss += red[p * 32 + t];
        float mk = amask[b * L2 + t];
        colscale[t] = mk / (mk * ss + 1e-10f);
    }
    __syncthreads();
    for (int idx = t; idx < L1 * L2; idx += 256) {
        int jj = idx & 31;
        sb[idx] = expf(sb[idx] - colmax[jj]) * colscale[jj];
    }
}

// ---------------- att = alpha @ aspect, written as bf16 into Xcat[:,300:600]
__global__ __launch_bounds__(256) void att_fused(const float* __restrict__ alpha,
                                                 const float* __restrict__ asp,
                                                 __hip_bfloat16* __restrict__ Xc) {
    __shared__ float aL[L2 * DIM];
    __shared__ float pL[32 * L2];
    int b = blockIdx.y, i0 = blockIdx.x * 32, t = threadIdx.x;
    for (int idx = t; idx < L2 * DIM; idx += 256) aL[idx] = asp[(size_t)b * L2 * DIM + idx];
    for (int idx = t; idx < 32 * L2; idx += 256) pL[idx] = alpha[((size_t)b * L1 + i0) * L2 + idx];
    __syncthreads();
    int d0 = t & 31, ib = t >> 5;
    #pragma unroll
    for (int p = 0; p < 4; ++p) {
        int i = ib + 8 * p;
        for (int q = 0; q < 10; ++q) {
            int d = d0 + 32 * q;
            if (d < DIM) {
                float a = 0.f;
                #pragma unroll
                for (int jj = 0; jj < L2; ++jj)
                    a = fmaf(pL[i * L2 + jj], aL[jj * DIM + d], a);
                Xc[((size_t)(b * L1 + i0 + i)) * XW + 300 + d] = __float2bfloat16(a);
            }
        }
    }
}

// ---------------- Xcat x-part: bf16 embedding gather + zero pad + zero row
__global__ void xcat_x(const int* __restrict__ cids,
                       const float* __restrict__ wordmat,
                       __hip_bfloat16* __restrict__ Xc,
                       float* __restrict__ zrow) {
    int row = blockIdx.x, t = threadIdx.x;
    if (row == 0 && t < 304) zrow[t] = 0.f;   // 1216B zero source row
    int id = cids[row];
    if (t < 300)
        Xc[(size_t)row * XW + t] = __float2bfloat16(wordmat[(size_t)id * DIM + t]);
    else if (t < 308)
        Xc[(size_t)row * XW + 600 + (t - 300)] = __float2bfloat16(0.f);
}

// ---------------- fused conv GEMM: (128 l) x (128 sent ch | 128 gate ch) per block
// K-loop: 19 chunks of 32 cin x 3 taps. MFMA 16x16x32 bf16, fp32 accum.
// Epilogue: bias + tanh*relu + maxpool over the block's 128 l -> partial max.
__global__ __launch_bounds__(256, 2) void conv_mfma(
        const __hip_bfloat16* __restrict__ Xc,
        const __hip_bfloat16* __restrict__ Wp,
        const float* __restrict__ zrow,
        const float* __restrict__ ctx_b,
        const float* __restrict__ gate_b,
        float* __restrict__ part) {
    __shared__ __align__(16) char lds[A_LDS_B + WP_HALF_B];  // 57.6 KB
    char* Alds = lds;
    char* Blds = lds + A_LDS_B;
    const int t = threadIdx.x;
    const int wave = t >> 6, lane = t & 63;
    const int lb = blockIdx.x >> 1, cb = blockIdx.x & 1;
    const int b = blockIdx.y;
    const int l0 = lb * 128;

    f32x4 acc[8][4];
    #pragma unroll
    for (int m = 0; m < 8; ++m)
        #pragma unroll
        for (int n = 0; n < 4; ++n) acc[m][n] = (f32x4)0.f;

    const char* XcB = (const char*)Xc;
    const char* zB = (const char*)zrow;
    const char* WpB = (const char*)Wp + (size_t)cb * (NKC * WP_HALF_B);

    for (int kc = 0; kc < NKC; ++kc) {
        // stage A: 130 rows x 64B = 520 chunks; source pre-swizzled (rule #21)
        #pragma unroll
        for (int i = 0; i < 3; ++i) {
            int chunk = (i * 4 + wave) * 64 + lane;
            if (chunk < 520) {
                int row = chunk >> 2, c = chunk & 3;
                int lp = l0 - 1 + row;
                int sc = (c ^ (row & 3)) << 4;
                const char* src = (lp >= 0 && lp < L1)
                    ? XcB + (size_t)(b * L1 + lp) * ROW_B + kc * 64 + sc
                    : zB + sc;
                gload_lds16(src, Alds + (i * 4 + wave) * 1024);
            }
        }
        // stage B: pure linear 48KB copy (fragment-linear prepack)
        const char* wsrc = WpB + (size_t)kc * WP_HALF_B;
        #pragma unroll
        for (int i = 0; i < 12; ++i) {
            int off = (i * 4 + wave) * 1024;
            gload_lds16(wsrc + off + lane * 16, Blds + off);
        }
        __syncthreads();
        // sentiment waves (0,1): weights zero for k>=300 -> skip kc>=10
        if (wave >= 2 || kc < 10) {
            #pragma unroll
            for (int tap = 0; tap < 3; ++tap) {
                bf16x8 af[8];
                #pragma unroll
                for (int m = 0; m < 8; ++m) {
                    int row = m * 16 + (lane & 15) + tap;
                    af[m] = *(const bf16x8*)(Alds + row * 64 +
                                             ((((lane >> 4) ^ row) & 3) << 4));
                }
                bf16x8 bfr[4];
                #pragma unroll
                for (int n = 0; n < 4; ++n)
                    bfr[n] = *(const bf16x8*)(Blds +
                              ((((tap * 16 + (wave << 2) + n) << 6) + lane) << 4));
                #pragma unroll
                for (int m = 0; m < 8; ++m)
                    #pragma unroll
                    for (int n = 0; n < 4; ++n)
                        acc[m][n] = __builtin_amdgcn_mfma_f32_16x16x32_bf16(
                            af[m], bfr[n], acc[m][n], 0, 0, 0);
            }
        }
        __syncthreads();
    }

    // epilogue: per 16-row slice, cross-wave combine sent x gate, maxpool
    const int c0 = cb * 128;
    const int cl = t & 127, rh = t >> 7;
    const float bs = ctx_b[c0 + cl];
    const float bg = gate_b[c0 + cl];
    float* ep = (float*)lds;  // [16][256] f32 = 16KB
    float pm = -1e30f;
    for (int ms = 0; ms < 8; ++ms) {
        __syncthreads();
        #pragma unroll
        for (int n = 0; n < 4; ++n) {
            int col = (wave << 6) + (n << 4) + (lane & 15);
            #pragma unroll
            for (int i2 = 0; i2 < 4; ++i2) {
                int r = ((lane >> 4) << 2) + i2;
                ep[r * 256 + col] = acc[ms][n][i2];
            }
        }
        __syncthreads();
        #pragma unroll
        for (int rr = 0; rr < 8; ++rr) {
            int r = rh * 8 + rr;
            float sv = ep[r * 256 + cl] + bs;
            float gv = ep[r * 256 + 128 + cl] + bg;
            pm = fmaxf(pm, tanhf(sv) * fmaxf(gv, 0.f));
        }
    }
    __syncthreads();
    float* red = (float*)lds;
    red[t] = pm;
    __syncthreads();
    if (t < 128)
        part[((size_t)b * 4 + lb) * 256 + c0 + cl] = fmaxf(red[t], red[t + 128]);
}

// ---------------- final: max over 4 l-blocks + linear
__global__ __launch_bounds__(256) void finalize(const float* __restrict__ part,
                                                const float* __restrict__ lin_w,
                                                const float* __restrict__ lin_b,
                                                float* __restrict__ out) {
    __shared__ float pl[256];
    __shared__ float red[256];
    int b = blockIdx.x, t = threadIdx.x;
    float p = part[((size_t)b * 4) * 256 + t];
    for (int lb = 1; lb < 4; ++lb)
        p = fmaxf(p, part[((size_t)b * 4 + lb) * 256 + t]);
    pl[t] = p;
    __syncthreads();
    for (int n = 0; n < NCLASS; ++n) {
        red[t] = pl[t] * lin_w[n * NC + t];
        __syncthreads();
        for (int sft = 128; sft > 0; sft >>= 1) {
            if (t < sft) red[t] += red[t + sft];
            __syncthreads();
        }
        if (t == 0) out[b * NCLASS + n] = red[0] + lin_b[n];
        __syncthreads();
    }
}

extern "C" void kernel_launch(void* const* d_in, const int* in_sizes, int n_in,
                              void* d_out, int out_size, void* d_ws, size_t ws_size,
                              hipStream_t stream) {
    const int* cids = (const int*)d_in[0];
    const int* aids = (const int*)d_in[2];
    const float* amask = (const float*)d_in[3];
    const float* wordmat = (const float*)d_in[4];
    const float* Wm = (const float*)d_in[5];
    const float* ctx_w = (const float*)d_in[6];
    const float* ctx_b = (const float*)d_in[7];
    const float* gate_w = (const float*)d_in[8];
    const float* gate_b = (const float*)d_in[9];
    const float* lin_w = (const float*)d_in[10];
    const float* lin_b = (const float*)d_in[11];
    float* out = (float*)d_out;

    // workspace (floats): asp | syb(+aliased part/zrow after s_fused) | sbuf | Wp | Xcat
    float* asp = (float*)d_ws;
    float* syb = asp + ASP_N;
    float* part = syb;                    // alias: syb dead after s_fused
    float* zrow = syb + BB * 4 * NC;      // 16B-aligned, zeroed in xcat_x
    float* sbuf = syb + SY_N;
    __hip_bfloat16* Wp = (__hip_bfloat16*)(sbuf + S_N);
    __hip_bfloat16* Xc = (__hip_bfloat16*)((char*)Wp + (size_t)WP_ELEMS * 2);

    prep_wp<<<(WP_ELEMS + 255) / 256, 256, 0, stream>>>(ctx_w, gate_w, Wp);
    gather_rows<<<BB * L2, 256, 0, stream>>>(aids, wordmat, asp);
    gemm_relu_sy<<<(BB * L2) / 32, 256, 0, stream>>>(asp, Wm, syb);
    s_fused<<<dim3(L1 / 32, BB), 256, 0, stream>>>(cids, wordmat, Wm, syb, sbuf);
    softmax_col<<<BB, 256, 0, stream>>>(sbuf, amask);
    att_fused<<<dim3(L1 / 32, BB), 256, 0, stream>>>(sbuf, asp, Xc);
    xcat_x<<<BB * L1, 320, 0, stream>>>(cids, wordmat, Xc, zrow);
    conv_mfma<<<dim3(8, BB), 256, 0, stream>>>(Xc, Wp, zrow, ctx_b, gate_b, part);
    finalize<<<BB, 256, 0, stream>>>(part, lin_w, lin_b, out);
}

// Round 3
// 334.808 us; speedup vs baseline: 10.0903x; 2.7883x over previous
//
#include <hip/hip_runtime.h>
#include <hip/hip_bf16.h>
#include <math.h>
#include <stdint.h>

#define VOCAB 50000
#define DIM 300
#define NC 256
#define KS 3
#define NCLASS 3
#define BB 128
#define L1 512
#define L2 32

#define XW 608          // padded cin width: [emb 300 | att 300 | 0 x8]
#define NKC 19          // conv K-chunks of 32 per tap
#define ROW_B (XW * 2)  // 1216 bytes per Xcat row
#define WP_HALF_B 49152
#define WP_ELEMS (2 * NKC * 3 * 16 * 64 * 8)
#define A_LDS_B 8448
#define WB_ELEMS (10 * 19 * 64 * 8)   // 97280: W fragments, 320x304 padded

typedef __attribute__((ext_vector_type(8))) short bf16x8;
typedef __attribute__((ext_vector_type(4))) float f32x4;

#define GLOBAL_AS __attribute__((address_space(1)))
#define LDS_AS __attribute__((address_space(3)))

__device__ __forceinline__ void gload_lds16(const void* g, void* l) {
    __builtin_amdgcn_global_load_lds((const GLOBAL_AS void*)g, (LDS_AS void*)l, 16, 0, 0);
}

// ---------------- conv weight pre-pack (fragment-linear)
__global__ void prep_wp(const float* __restrict__ ctx_w,
                        const float* __restrict__ gate_w,
                        __hip_bfloat16* __restrict__ Wp) {
    int idx = blockIdx.x * 256 + threadIdx.x;
    if (idx >= WP_ELEMS) return;
    int j = idx & 7;
    int r1 = idx >> 3;
    int lane = r1 & 63;
    int r2 = r1 >> 6;
    int nf = r2 & 15;
    int r3 = r2 >> 4;
    int tap = r3 % 3;
    int r4 = r3 / 3;
    int kc = r4 % NKC;
    int cbv = r4 / NKC;
    int k = kc * 32 + ((lane >> 4) << 3) + j;
    int nl = (nf << 4) + (lane & 15);
    int ch = cbv * 128 + (nl & 127);
    float v = 0.f;
    if ((nl >> 7) == 0) {
        if (k < 300) v = ctx_w[(ch * DIM + k) * KS + tap];
    } else {
        if (k < 600) v = gate_w[(ch * 2 * DIM + k) * KS + tap];
    }
    Wp[idx] = __float2bfloat16(v);
}

// ---------------- W pre-pack for sx/sy GEMMs: Wb[kc][nf][lane][8], zero-padded
__global__ void prep_wb(const float* __restrict__ Wm,
                        __hip_bfloat16* __restrict__ Wb) {
    int idx = blockIdx.x * 256 + threadIdx.x;
    if (idx >= WB_ELEMS) return;
    int j = idx & 7;
    int l = (idx >> 3) & 63;
    int r = idx >> 9;
    int nf = r % 19, kc = r / 19;
    int k = kc * 32 + ((l >> 4) << 3) + j;
    int n = nf * 16 + (l & 15);
    float v = (k < 300 && n < 300) ? Wm[k * DIM + n] : 0.f;
    Wb[idx] = __float2bfloat16(v);
}

// ---------------- aspect gather: fp32 (for att_fused) + bf16 padded + sy pad zeros
__global__ void gather_rows(const int* __restrict__ ids,
                            const float* __restrict__ wordmat,
                            float* __restrict__ asp,
                            __hip_bfloat16* __restrict__ aspb,
                            __hip_bfloat16* __restrict__ syb) {
    int row = blockIdx.x;
    int id = ids[row];
    const float* src = wordmat + (size_t)id * DIM;
    for (int d = threadIdx.x; d < 320; d += blockDim.x) {
        if (d < DIM) {
            float v = src[d];
            asp[(size_t)row * DIM + d] = v;
            aspb[(size_t)row * 320 + d] = __float2bfloat16(v);
        } else {
            aspb[(size_t)row * 320 + d] = __float2bfloat16(0.f);
            if (d >= 304) syb[(size_t)row * 320 + d] = __float2bfloat16(0.f);
        }
    }
}

// ---------------- Xcat x-part: bf16 embedding gather + pad + zero row
__global__ void xcat_x(const int* __restrict__ cids,
                       const float* __restrict__ wordmat,
                       __hip_bfloat16* __restrict__ Xc,
                       float* __restrict__ zrow) {
    int row = blockIdx.x, t = threadIdx.x;
    if (row == 0 && t < 304) zrow[t] = 0.f;
    int id = cids[row];
    if (t < 300)
        Xc[(size_t)row * XW + t] = __float2bfloat16(wordmat[(size_t)id * DIM + t]);
    else if (t < 308)
        Xc[(size_t)row * XW + 600 + (t - 300)] = __float2bfloat16(0.f);
}

// ---------------- sy = relu(aspect @ W) via MFMA; operands direct-from-global
__global__ __launch_bounds__(256, 2) void sy_mfma(
        const __hip_bfloat16* __restrict__ aspb,
        const __hip_bfloat16* __restrict__ Wb,
        __hip_bfloat16* __restrict__ syb) {
    const int t = threadIdx.x, wave = t >> 6, l = t & 63;
    const int lane15 = l & 15, lq = l >> 4;
    const int g = blockIdx.x * 64 + wave * 16 + lane15;
    f32x4 acc[19];
    #pragma unroll
    for (int nf = 0; nf < 19; ++nf) acc[nf] = (f32x4)0.f;
    const bf16x8* Arow = (const bf16x8*)((const char*)aspb + (size_t)g * 640);
    const bf16x8* WbV = (const bf16x8*)Wb;
    for (int kc = 0; kc < 10; ++kc) {
        bf16x8 af = Arow[kc * 4 + lq];
        #pragma unroll
        for (int nf = 0; nf < 19; ++nf)
            acc[nf] = __builtin_amdgcn_mfma_f32_16x16x32_bf16(
                af, WbV[(kc * 19 + nf) * 64 + l], acc[nf], 0, 0, 0);
    }
    #pragma unroll
    for (int nf = 0; nf < 19; ++nf) {
        int col = nf * 16 + lane15;
        #pragma unroll
        for (int i2 = 0; i2 < 4; ++i2) {
            int row = blockIdx.x * 64 + wave * 16 + lq * 4 + i2;
            syb[(size_t)row * 320 + col] = __float2bfloat16(fmaxf(acc[nf][i2], 0.f));
        }
    }
}

// ---------------- fused sx+s: phase1 sx=relu(ctx@W) in regs (16x304/wave),
// phase2 redistribute via wave-private LDS, s = sx @ sy^T. No syncthreads.
__global__ __launch_bounds__(256, 2) void sxs_mfma(
        const __hip_bfloat16* __restrict__ Xc,
        const __hip_bfloat16* __restrict__ Wb,
        const __hip_bfloat16* __restrict__ syb,
        float* __restrict__ s) {
    __shared__ __align__(16) char sxL[4 * 16 * 640];  // 40KB, 10KB per wave
    const int t = threadIdx.x, wave = t >> 6, l = t & 63;
    const int lane15 = l & 15, lq = l >> 4;
    const int lb = blockIdx.x, b = blockIdx.y;
    const int g = b * L1 + lb * 64 + wave * 16 + lane15;

    f32x4 acc[19];
    #pragma unroll
    for (int nf = 0; nf < 19; ++nf) acc[nf] = (f32x4)0.f;

    const bf16x8* Arow = (const bf16x8*)((const char*)Xc + (size_t)g * ROW_B);
    const bf16x8* WbV = (const bf16x8*)Wb;
    for (int kc = 0; kc < 10; ++kc) {
        bf16x8 af = Arow[kc * 4 + lq];
        #pragma unroll
        for (int nf = 0; nf < 19; ++nf)
            acc[nf] = __builtin_amdgcn_mfma_f32_16x16x32_bf16(
                af, WbV[(kc * 19 + nf) * 64 + l], acc[nf], 0, 0, 0);
    }

    char* sxW = sxL + wave * (16 * 640);
    // zero only the never-written phys slots of the kc=9 chunk (cols 304..319)
    if (l < 32) {
        int row = l >> 1;
        int phys = (2 + (l & 1)) ^ ((row >> 2) & 3);
        *(f32x4*)(sxW + row * 640 + 576 + phys * 16) = (f32x4)0.f;
    }
    #pragma unroll
    for (int nf = 0; nf < 19; ++nf) {
        int col = nf * 16 + lane15;
        #pragma unroll
        for (int i2 = 0; i2 < 4; ++i2) {
            int row = lq * 4 + i2;
            int off = row * 640 + ((col >> 5) << 6) +
                      ((((col >> 3) & 3) ^ ((row >> 2) & 3)) << 4) + ((col & 7) << 1);
            *(__hip_bfloat16*)(sxW + off) = __float2bfloat16(fmaxf(acc[nf][i2], 0.f));
        }
    }
    f32x4 acc2[2];
    acc2[0] = (f32x4)0.f;
    acc2[1] = (f32x4)0.f;
    const bf16x8* syV = (const bf16x8*)syb + (size_t)b * 32 * 40;
    for (int kc = 0; kc < 10; ++kc) {
        bf16x8 af2 = *(const bf16x8*)(sxW + lane15 * 640 + kc * 64 +
                                      ((lq ^ ((lane15 >> 2) & 3)) << 4));
        #pragma unroll
        for (int nj = 0; nj < 2; ++nj) {
            bf16x8 bfj = syV[(nj * 16 + lane15) * 40 + kc * 4 + lq];
            acc2[nj] = __builtin_amdgcn_mfma_f32_16x16x32_bf16(af2, bfj, acc2[nj], 0, 0, 0);
        }
    }
    #pragma unroll
    for (int nj = 0; nj < 2; ++nj)
        #pragma unroll
        for (int i2 = 0; i2 < 4; ++i2) {
            int i = lb * 64 + wave * 16 + lq * 4 + i2;
            s[((size_t)b * L1 + i) * L2 + nj * 16 + lane15] = acc2[nj][i2];
        }
}

// ---------------- softmax over dim=1 (L1) per (b,j)
__global__ __launch_bounds__(256) void softmax_col(float* __restrict__ s,
                                                   const float* __restrict__ amask) {
    __shared__ float red[256];
    __shared__ float colmax[L2], colscale[L2];
    int b = blockIdx.x, t = threadIdx.x;
    int j = t & 31, ii = t >> 5;
    float* sb = s + (size_t)b * L1 * L2;
    float m = -1e30f;
    for (int i = ii; i < L1; i += 8) m = fmaxf(m, sb[i * L2 + j]);
    red[t] = m;
    __syncthreads();
    if (t < 32) {
        float mm = red[t];
        for (int p = 1; p < 8; ++p) mm = fmaxf(mm, red[p * 32 + t]);
        colmax[t] = mm;
    }
    __syncthreads();
    float cm = colmax[j];
    float sum = 0.f;
    for (int i = ii; i < L1; i += 8) sum += expf(sb[i * L2 + j] - cm);
    red[t] = sum;
    __syncthreads();
    if (t < 32) {
        float ss = 0.f;
        for (int p = 0; p < 8; ++p) ss += red[p * 32 + t];
        float mk = amask[b * L2 + t];
        colscale[t] = mk / (mk * ss + 1e-10f);
    }
    __syncthreads();
    for (int idx = t; idx < L1 * L2; idx += 256) {
        int jj = idx & 31;
        sb[idx] = expf(sb[idx] - colmax[jj]) * colscale[jj];
    }
}

// ---------------- att = alpha @ aspect, bf16 into Xcat[:,300:600]
__global__ __launch_bounds__(256) void att_fused(const float* __restrict__ alpha,
                                                 const float* __restrict__ asp,
                                                 __hip_bfloat16* __restrict__ Xc) {
    __shared__ float aL[L2 * DIM];
    __shared__ float pL[32 * L2];
    int b = blockIdx.y, i0 = blockIdx.x * 32, t = threadIdx.x;
    for (int idx = t; idx < L2 * DIM; idx += 256) aL[idx] = asp[(size_t)b * L2 * DIM + idx];
    for (int idx = t; idx < 32 * L2; idx += 256) pL[idx] = alpha[((size_t)b * L1 + i0) * L2 + idx];
    __syncthreads();
    int d0 = t & 31, ib = t >> 5;
    #pragma unroll
    for (int p = 0; p < 4; ++p) {
        int i = ib + 8 * p;
        for (int q = 0; q < 10; ++q) {
            int d = d0 + 32 * q;
            if (d < DIM) {
                float a = 0.f;
                #pragma unroll
                for (int jj = 0; jj < L2; ++jj)
                    a = fmaf(pL[i * L2 + jj], aL[jj * DIM + d], a);
                Xc[((size_t)(b * L1 + i0 + i)) * XW + 300 + d] = __float2bfloat16(a);
            }
        }
    }
}

// ---------------- fused conv GEMM + epilogue (unchanged from round 1)
__global__ __launch_bounds__(256, 2) void conv_mfma(
        const __hip_bfloat16* __restrict__ Xc,
        const __hip_bfloat16* __restrict__ Wp,
        const float* __restrict__ zrow,
        const float* __restrict__ ctx_b,
        const float* __restrict__ gate_b,
        float* __restrict__ part) {
    __shared__ __align__(16) char lds[A_LDS_B + WP_HALF_B];
    char* Alds = lds;
    char* Blds = lds + A_LDS_B;
    const int t = threadIdx.x;
    const int wave = t >> 6, lane = t & 63;
    const int lb = blockIdx.x >> 1, cb = blockIdx.x & 1;
    const int b = blockIdx.y;
    const int l0 = lb * 128;

    f32x4 acc[8][4];
    #pragma unroll
    for (int m = 0; m < 8; ++m)
        #pragma unroll
        for (int n = 0; n < 4; ++n) acc[m][n] = (f32x4)0.f;

    const char* XcB = (const char*)Xc;
    const char* zB = (const char*)zrow;
    const char* WpB = (const char*)Wp + (size_t)cb * (NKC * WP_HALF_B);

    for (int kc = 0; kc < NKC; ++kc) {
        #pragma unroll
        for (int i = 0; i < 3; ++i) {
            int chunk = (i * 4 + wave) * 64 + lane;
            if (chunk < 520) {
                int row = chunk >> 2, c = chunk & 3;
                int lp = l0 - 1 + row;
                int sc = (c ^ (row & 3)) << 4;
                const char* src = (lp >= 0 && lp < L1)
                    ? XcB + (size_t)(b * L1 + lp) * ROW_B + kc * 64 + sc
                    : zB + sc;
                gload_lds16(src, Alds + (i * 4 + wave) * 1024);
            }
        }
        const char* wsrc = WpB + (size_t)kc * WP_HALF_B;
        #pragma unroll
        for (int i = 0; i < 12; ++i) {
            int off = (i * 4 + wave) * 1024;
            gload_lds16(wsrc + off + lane * 16, Blds + off);
        }
        __syncthreads();
        if (wave >= 2 || kc < 10) {
            #pragma unroll
            for (int tap = 0; tap < 3; ++tap) {
                bf16x8 af[8];
                #pragma unroll
                for (int m = 0; m < 8; ++m) {
                    int row = m * 16 + (lane & 15) + tap;
                    af[m] = *(const bf16x8*)(Alds + row * 64 +
                                             ((((lane >> 4) ^ row) & 3) << 4));
                }
                bf16x8 bfr[4];
                #pragma unroll
                for (int n = 0; n < 4; ++n)
                    bfr[n] = *(const bf16x8*)(Blds +
                              ((((tap * 16 + (wave << 2) + n) << 6) + lane) << 4));
                #pragma unroll
                for (int m = 0; m < 8; ++m)
                    #pragma unroll
                    for (int n = 0; n < 4; ++n)
                        acc[m][n] = __builtin_amdgcn_mfma_f32_16x16x32_bf16(
                            af[m], bfr[n], acc[m][n], 0, 0, 0);
            }
        }
        __syncthreads();
    }

    const int c0 = cb * 128;
    const int cl = t & 127, rh = t >> 7;
    const float bs = ctx_b[c0 + cl];
    const float bg = gate_b[c0 + cl];
    float* ep = (float*)lds;
    float pm = -1e30f;
    for (int ms = 0; ms < 8; ++ms) {
        __syncthreads();
        #pragma unroll
        for (int n = 0; n < 4; ++n) {
            int col = (wave << 6) + (n << 4) + (lane & 15);
            #pragma unroll
            for (int i2 = 0; i2 < 4; ++i2) {
                int r = ((lane >> 4) << 2) + i2;
                ep[r * 256 + col] = acc[ms][n][i2];
            }
        }
        __syncthreads();
        #pragma unroll
        for (int rr = 0; rr < 8; ++rr) {
            int r = rh * 8 + rr;
            float sv = ep[r * 256 + cl] + bs;
            float gv = ep[r * 256 + 128 + cl] + bg;
            pm = fmaxf(pm, tanhf(sv) * fmaxf(gv, 0.f));
        }
    }
    __syncthreads();
    float* red = (float*)lds;
    red[t] = pm;
    __syncthreads();
    if (t < 128)
        part[((size_t)b * 4 + lb) * 256 + c0 + cl] = fmaxf(red[t], red[t + 128]);
}

// ---------------- final: max over 4 l-blocks + linear
__global__ __launch_bounds__(256) void finalize(const float* __restrict__ part,
                                                const float* __restrict__ lin_w,
                                                const float* __restrict__ lin_b,
                                                float* __restrict__ out) {
    __shared__ float pl[256];
    __shared__ float red[256];
    int b = blockIdx.x, t = threadIdx.x;
    float p = part[((size_t)b * 4) * 256 + t];
    for (int lb = 1; lb < 4; ++lb)
        p = fmaxf(p, part[((size_t)b * 4 + lb) * 256 + t]);
    pl[t] = p;
    __syncthreads();
    for (int n = 0; n < NCLASS; ++n) {
        red[t] = pl[t] * lin_w[n * NC + t];
        __syncthreads();
        for (int sft = 128; sft > 0; sft >>= 1) {
            if (t < sft) red[t] += red[t + sft];
            __syncthreads();
        }
        if (t == 0) out[b * NCLASS + n] = red[0] + lin_b[n];
        __syncthreads();
    }
}

extern "C" void kernel_launch(void* const* d_in, const int* in_sizes, int n_in,
                              void* d_out, int out_size, void* d_ws, size_t ws_size,
                              hipStream_t stream) {
    const int* cids = (const int*)d_in[0];
    const int* aids = (const int*)d_in[2];
    const float* amask = (const float*)d_in[3];
    const float* wordmat = (const float*)d_in[4];
    const float* Wm = (const float*)d_in[5];
    const float* ctx_w = (const float*)d_in[6];
    const float* ctx_b = (const float*)d_in[7];
    const float* gate_w = (const float*)d_in[8];
    const float* gate_b = (const float*)d_in[9];
    const float* lin_w = (const float*)d_in[10];
    const float* lin_b = (const float*)d_in[11];
    float* out = (float*)d_out;

    float* asp = (float*)d_ws;                       // 1,228,800 f
    float* sbuf = asp + 1228800;                     // 2,097,152 f
    float* part = sbuf + 2097152;                    // 131,072 f
    float* zrow = part + 131072;                     // 320 f
    __hip_bfloat16* aspb = (__hip_bfloat16*)(zrow + 320);   // 1,310,720 bf16
    __hip_bfloat16* sybf = aspb + 1310720;                  // 1,310,720 bf16
    __hip_bfloat16* Wb = sybf + 1310720;                    // 97,280 bf16
    __hip_bfloat16* Wp = Wb + WB_ELEMS;                     // 1,867,776 bf16
    __hip_bfloat16* Xc = Wp + WP_ELEMS;                     // 39,845,888 bf16

    prep_wp<<<(WP_ELEMS + 255) / 256, 256, 0, stream>>>(ctx_w, gate_w, Wp);
    prep_wb<<<(WB_ELEMS + 255) / 256, 256, 0, stream>>>(Wm, Wb);
    gather_rows<<<BB * L2, 256, 0, stream>>>(aids, wordmat, asp, aspb, sybf);
    xcat_x<<<BB * L1, 320, 0, stream>>>(cids, wordmat, Xc, zrow);
    sy_mfma<<<(BB * L2) / 64, 256, 0, stream>>>(aspb, Wb, sybf);
    sxs_mfma<<<dim3(L1 / 64, BB), 256, 0, stream>>>(Xc, Wb, sybf, sbuf);
    softmax_col<<<BB, 256, 0, stream>>>(sbuf, amask);
    att_fused<<<dim3(L1 / 32, BB), 256, 0, stream>>>(sbuf, asp, Xc);
    conv_mfma<<<dim3(8, BB), 256, 0, stream>>>(Xc, Wp, zrow, ctx_b, gate_b, part);
    finalize<<<BB, 256, 0, stream>>>(part, lin_w, lin_b, out);
}

// Round 4
// 310.506 us; speedup vs baseline: 10.8800x; 1.0783x over previous
//
#include <hip/hip_runtime.h>
#include <hip/hip_bf16.h>
#include <math.h>
#include <stdint.h>

#define DIM 300
#define NC 256
#define KS 3
#define NCLASS 3
#define BB 128
#define L1 512
#define L2 32

#define XW 608            // Xc row: [emb 0..299 | 0 300..303 | att 304..603 | 0 604..607]
#define XROWS 514         // guard row + 512 + guard row, per batch
#define ROW_B (XW * 2)    // 1216 bytes
#define NKC 19
#define WP2_ELEMS (2 * 4 * 19 * 3 * 4 * 64 * 8)   // 933,888
#define WB_ELEMS (10 * 19 * 64 * 8)               // 97,280
#define WAVE_WP_B (19 * 3 * 4 * 1024)             // 233,472 B per (cb,wave)

typedef __attribute__((ext_vector_type(8))) short bf16x8;
typedef __attribute__((ext_vector_type(4))) short bf16x4;
typedef __attribute__((ext_vector_type(4))) float f32x4;

static __device__ __forceinline__ short bfr(float x) {
    __hip_bfloat16 h = __float2bfloat16(x);
    return *(short*)&h;
}

// ---------------- conv weight pre-pack: Wp2[cb][wave][kc][tap][n][lane][8]
__global__ void prep_wp(const float* __restrict__ ctx_w,
                        const float* __restrict__ gate_w,
                        __hip_bfloat16* __restrict__ Wp2) {
    int idx = blockIdx.x * 256 + threadIdx.x;
    if (idx >= WP2_ELEMS) return;
    int jj = idx & 7;
    int lane = (idx >> 3) & 63;
    int n = (idx >> 9) & 3;
    int rest = idx >> 11;
    int tap = rest % 3;
    int r2 = rest / 3;
    int kc = r2 % 19;
    int w = r2 / 19;
    int wave = w & 3, cbv = w >> 2;
    int k = kc * 32 + ((lane >> 4) << 3) + jj;
    int nl = wave * 64 + n * 16 + (lane & 15);
    float v = 0.f;
    if (nl < 128) {                    // sentiment channels
        int ch = cbv * 128 + nl;
        if (k < 300) v = ctx_w[(ch * DIM + k) * KS + tap];
    } else {                           // gate channels
        int ch = cbv * 128 + (nl - 128);
        if (k < 300) v = gate_w[(ch * 2 * DIM + k) * KS + tap];
        else if (k >= 304 && k < 604) v = gate_w[(ch * 2 * DIM + (k - 4)) * KS + tap];
    }
    Wp2[idx] = __float2bfloat16(v);
}

// ---------------- W pre-pack for sx/sy GEMMs (zero-padded)
__global__ void prep_wb(const float* __restrict__ Wm,
                        __hip_bfloat16* __restrict__ Wb) {
    int idx = blockIdx.x * 256 + threadIdx.x;
    if (idx >= WB_ELEMS) return;
    int j = idx & 7;
    int l = (idx >> 3) & 63;
    int r = idx >> 9;
    int nf = r % 19, kc = r / 19;
    int k = kc * 32 + ((l >> 4) << 3) + j;
    int n = nf * 16 + (l & 15);
    float v = (k < 300 && n < 300) ? Wm[k * DIM + n] : 0.f;
    Wb[idx] = __float2bfloat16(v);
}

// ---------------- aspect gather: fp32 + bf16 padded + sy pad zeros
__global__ void gather_rows(const int* __restrict__ ids,
                            const float* __restrict__ wordmat,
                            float* __restrict__ asp,
                            __hip_bfloat16* __restrict__ aspb,
                            __hip_bfloat16* __restrict__ syb) {
    int row = blockIdx.x;
    int id = ids[row];
    const float* src = wordmat + (size_t)id * DIM;
    for (int d = threadIdx.x; d < 320; d += blockDim.x) {
        if (d < DIM) {
            float v = src[d];
            asp[(size_t)row * DIM + d] = v;
            aspb[(size_t)row * 320 + d] = __float2bfloat16(v);
        } else {
            aspb[(size_t)row * 320 + d] = __float2bfloat16(0.f);
            if (d >= 304) syb[(size_t)row * 320 + d] = __float2bfloat16(0.f);
        }
    }
}

// ---------------- aspect B-frag pack for att GEMM: aspf[b][nf][lane][8]
__global__ void prep_aspf(const float* __restrict__ asp,
                          __hip_bfloat16* __restrict__ aspf) {
    int idx = blockIdx.x * 256 + threadIdx.x;
    if (idx >= BB * 19 * 512) return;
    int jj = idx & 7;
    int lane = (idx >> 3) & 63;
    int r = idx >> 9;
    int nf = r % 19, b = r / 19;
    int j = ((lane >> 4) << 3) + jj;
    int col = nf * 16 + (lane & 15);
    float v = (col < 300) ? asp[((size_t)b * L2 + j) * DIM + col] : 0.f;
    aspf[idx] = __float2bfloat16(v);
}

// ---------------- Xcat x-part: vectorized bf16 gather + pad + guard rows
__global__ __launch_bounds__(256) void xcat_x(const int* __restrict__ cids,
                                              const float* __restrict__ wordmat,
                                              __hip_bfloat16* __restrict__ Xc) {
    int t = threadIdx.x;
    int rloc = t >> 5, lane = t & 31;
    int row = blockIdx.x * 8 + rloc;          // 0..65535
    int b = row >> 9, l = row & 511;
    size_t id = (size_t)cids[row];
    const float4* src = (const float4*)(wordmat + id * DIM);
    __hip_bfloat16* dst = Xc + ((size_t)b * XROWS + 1 + l) * XW;
    #pragma unroll
    for (int c = lane; c < 76; c += 32) {
        bf16x4 o;
        if (c < 75) {
            float4 f = src[c];
            o[0] = bfr(f.x); o[1] = bfr(f.y); o[2] = bfr(f.z); o[3] = bfr(f.w);
        } else {
            o = (bf16x4)0;   // cols 300..303
        }
        ((bf16x4*)dst)[c] = o;
    }
    // zero guard rows (256 of them), 1216B each via 8B stores
    if (blockIdx.x < 256 && t < 152) {
        int b2 = blockIdx.x >> 1;
        int gr = (blockIdx.x & 1) ? (XROWS - 1) : 0;
        ((bf16x4*)(Xc + ((size_t)b2 * XROWS + gr) * XW))[t] = (bf16x4)0;
    }
}

// ---------------- sy = relu(aspect @ W) via MFMA, direct-from-global
__global__ __launch_bounds__(256, 2) void sy_mfma(
        const __hip_bfloat16* __restrict__ aspb,
        const __hip_bfloat16* __restrict__ Wb,
        __hip_bfloat16* __restrict__ syb) {
    const int t = threadIdx.x, wave = t >> 6, l = t & 63;
    const int lane15 = l & 15, lq = l >> 4;
    const int g = blockIdx.x * 64 + wave * 16 + lane15;
    f32x4 acc[19];
    #pragma unroll
    for (int nf = 0; nf < 19; ++nf) acc[nf] = (f32x4)0.f;
    const bf16x8* Arow = (const bf16x8*)((const char*)aspb + (size_t)g * 640);
    const bf16x8* WbV = (const bf16x8*)Wb;
    for (int kc = 0; kc < 10; ++kc) {
        bf16x8 af = Arow[kc * 4 + lq];
        #pragma unroll
        for (int nf = 0; nf < 19; ++nf)
            acc[nf] = __builtin_amdgcn_mfma_f32_16x16x32_bf16(
                af, WbV[(kc * 19 + nf) * 64 + l], acc[nf], 0, 0, 0);
    }
    #pragma unroll
    for (int nf = 0; nf < 19; ++nf) {
        int col = nf * 16 + lane15;
        #pragma unroll
        for (int i2 = 0; i2 < 4; ++i2) {
            int row = blockIdx.x * 64 + wave * 16 + lq * 4 + i2;
            syb[(size_t)row * 320 + col] = __float2bfloat16(fmaxf(acc[nf][i2], 0.f));
        }
    }
}

// ---------------- fused sx+s (guard-row layout), no syncthreads
__global__ __launch_bounds__(256, 2) void sxs_mfma(
        const __hip_bfloat16* __restrict__ Xc,
        const __hip_bfloat16* __restrict__ Wb,
        const __hip_bfloat16* __restrict__ syb,
        float* __restrict__ s) {
    __shared__ __align__(16) char sxL[4 * 16 * 640];  // 40KB, wave-private
    const int t = threadIdx.x, wave = t >> 6, l = t & 63;
    const int lane15 = l & 15, lq = l >> 4;
    const int lb = blockIdx.x, b = blockIdx.y;
    const int g = b * XROWS + 1 + lb * 64 + wave * 16 + lane15;

    f32x4 acc[19];
    #pragma unroll
    for (int nf = 0; nf < 19; ++nf) acc[nf] = (f32x4)0.f;

    const bf16x8* Arow = (const bf16x8*)((const char*)Xc + (size_t)g * ROW_B);
    const bf16x8* WbV = (const bf16x8*)Wb;
    for (int kc = 0; kc < 10; ++kc) {
        bf16x8 af = Arow[kc * 4 + lq];
        #pragma unroll
        for (int nf = 0; nf < 19; ++nf)
            acc[nf] = __builtin_amdgcn_mfma_f32_16x16x32_bf16(
                af, WbV[(kc * 19 + nf) * 64 + l], acc[nf], 0, 0, 0);
    }

    char* sxW = sxL + wave * (16 * 640);
    if (l < 32) {
        int row = l >> 1;
        int phys = (2 + (l & 1)) ^ ((row >> 2) & 3);
        *(f32x4*)(sxW + row * 640 + 576 + phys * 16) = (f32x4)0.f;
    }
    #pragma unroll
    for (int nf = 0; nf < 19; ++nf) {
        int col = nf * 16 + lane15;
        #pragma unroll
        for (int i2 = 0; i2 < 4; ++i2) {
            int row = lq * 4 + i2;
            int off = row * 640 + ((col >> 5) << 6) +
                      ((((col >> 3) & 3) ^ ((row >> 2) & 3)) << 4) + ((col & 7) << 1);
            *(__hip_bfloat16*)(sxW + off) = __float2bfloat16(fmaxf(acc[nf][i2], 0.f));
        }
    }
    f32x4 acc2[2];
    acc2[0] = (f32x4)0.f;
    acc2[1] = (f32x4)0.f;
    const bf16x8* syV = (const bf16x8*)syb + (size_t)b * 32 * 40;
    for (int kc = 0; kc < 10; ++kc) {
        bf16x8 af2 = *(const bf16x8*)(sxW + lane15 * 640 + kc * 64 +
                                      ((lq ^ ((lane15 >> 2) & 3)) << 4));
        #pragma unroll
        for (int nj = 0; nj < 2; ++nj) {
            bf16x8 bfj = syV[(nj * 16 + lane15) * 40 + kc * 4 + lq];
            acc2[nj] = __builtin_amdgcn_mfma_f32_16x16x32_bf16(af2, bfj, acc2[nj], 0, 0, 0);
        }
    }
    #pragma unroll
    for (int nj = 0; nj < 2; ++nj)
        #pragma unroll
        for (int i2 = 0; i2 < 4; ++i2) {
            int i = lb * 64 + wave * 16 + lq * 4 + i2;
            s[((size_t)b * L1 + i) * L2 + nj * 16 + lane15] = acc2[nj][i2];
        }
}

// ---------------- softmax over dim=1 (L1): single-read, bf16 alpha out
__global__ __launch_bounds__(256) void softmax_col(const float* __restrict__ s,
                                                   const float* __restrict__ amask,
                                                   __hip_bfloat16* __restrict__ albf) {
    __shared__ float red[256];
    __shared__ float cmax[16], cscale[16];
    int b = blockIdx.x, jh = blockIdx.y, t = threadIdx.x;
    int jl = t & 15, j = jh * 16 + jl, ii = t >> 4;
    const float* sb = s + (size_t)b * L1 * L2;
    float v[32];
    float m = -1e30f;
    #pragma unroll
    for (int q = 0; q < 32; ++q) {
        v[q] = sb[(size_t)(ii + q * 16) * L2 + j];
        m = fmaxf(m, v[q]);
    }
    red[t] = m;
    __syncthreads();
    if (t < 16) {
        float mm = red[t];
        for (int p = 1; p < 16; ++p) mm = fmaxf(mm, red[p * 16 + t]);
        cmax[t] = mm;
    }
    __syncthreads();
    float cm = cmax[jl];
    float sum = 0.f;
    #pragma unroll
    for (int q = 0; q < 32; ++q) {
        v[q] = expf(v[q] - cm);
        sum += v[q];
    }
    red[t] = sum;
    __syncthreads();
    if (t < 16) {
        float ss = 0.f;
        for (int p = 0; p < 16; ++p) ss += red[p * 16 + t];
        float mk = amask[b * L2 + jh * 16 + t];
        cscale[t] = mk / (mk * ss + 1e-10f);
    }
    __syncthreads();
    float sc = cscale[jl];
    #pragma unroll
    for (int q = 0; q < 32; ++q)
        albf[(size_t)(b * L1 + ii + q * 16) * L2 + j] = __float2bfloat16(v[q] * sc);
}

// ---------------- att = alpha @ aspect via MFMA (K=32 single chunk) -> Xc[304..607]
__global__ __launch_bounds__(256, 2) void att_mfma(
        const __hip_bfloat16* __restrict__ albf,
        const __hip_bfloat16* __restrict__ aspf,
        __hip_bfloat16* __restrict__ Xc) {
    __shared__ __align__(16) __hip_bfloat16 tl[4][16][320];  // 40KB, wave-private
    const int t = threadIdx.x, wave = t >> 6, l = t & 63;
    const int lane15 = l & 15, lq = l >> 4;
    const int ax = blockIdx.x, b = blockIdx.y;
    const int row = ax * 64 + wave * 16 + lane15;

    bf16x8 af = *(const bf16x8*)(albf + ((size_t)b * L1 + row) * L2 + lq * 8);
    f32x4 acc[19];
    #pragma unroll
    for (int nf = 0; nf < 19; ++nf) acc[nf] = (f32x4)0.f;
    const bf16x8* bp = (const bf16x8*)aspf + (size_t)b * 19 * 64;
    #pragma unroll
    for (int nf = 0; nf < 19; ++nf)
        acc[nf] = __builtin_amdgcn_mfma_f32_16x16x32_bf16(af, bp[nf * 64 + l], acc[nf], 0, 0, 0);

    #pragma unroll
    for (int nf = 0; nf < 19; ++nf) {
        int col = nf * 16 + lane15;
        #pragma unroll
        for (int i2 = 0; i2 < 4; ++i2)
            tl[wave][lq * 4 + i2][col] = __float2bfloat16(acc[nf][i2]);
    }
    // wave-private transpose -> coalesced 16B stores at col 304
    for (int r = 0; r < 16; ++r) {
        if (l < 38) {
            bf16x8 vv = *(const bf16x8*)&tl[wave][r][l * 8];
            *(bf16x8*)(Xc + ((size_t)b * XROWS + 1 + ax * 64 + wave * 16 + r) * XW + 304 + l * 8) = vv;
        }
    }
}

// ---------------- conv GEMM: barrier-free K-loop, direct-global A and B
__global__ __launch_bounds__(256, 2) void conv_mfma(
        const __hip_bfloat16* __restrict__ Xc,
        const __hip_bfloat16* __restrict__ Wp2,
        const float* __restrict__ ctx_b,
        const float* __restrict__ gate_b,
        float* __restrict__ part) {
    __shared__ float ep[16 * 256];   // 16KB, epilogue only
    const int t = threadIdx.x, wave = t >> 6, lane = t & 63;
    const int lane15 = lane & 15, lq = lane >> 4;
    const int lb = blockIdx.x >> 1, cb = blockIdx.x & 1;
    const int b = blockIdx.y, l0 = lb * 128;

    f32x4 acc[8][4];
    #pragma unroll
    for (int m = 0; m < 8; ++m)
        #pragma unroll
        for (int n = 0; n < 4; ++n) acc[m][n] = (f32x4)0.f;

    const char* XcB = (const char*)Xc;
    const char* aRow[8];
    #pragma unroll
    for (int m = 0; m < 8; ++m)
        aRow[m] = XcB + ((size_t)(b * XROWS + l0 + m * 16 + lane15)) * ROW_B + lq * 16;
    const char* bbase = (const char*)Wp2 + (size_t)(cb * 4 + wave) * WAVE_WP_B + lane * 16;

    const int kcEnd = (wave < 2) ? 10 : 19;   // sentiment weights zero for kc>=10
    for (int kc = 0; kc < kcEnd; ++kc) {
        #pragma unroll
        for (int tap = 0; tap < 3; ++tap) {
            bf16x8 bw[4];
            #pragma unroll
            for (int n = 0; n < 4; ++n)
                bw[n] = *(const bf16x8*)(bbase + (size_t)((kc * 3 + tap) * 4 + n) * 1024);
            bf16x8 af[8];
            #pragma unroll
            for (int m = 0; m < 8; ++m)
                af[m] = *(const bf16x8*)(aRow[m] + kc * 64 + tap * ROW_B);
            #pragma unroll
            for (int m = 0; m < 8; ++m)
                #pragma unroll
                for (int n = 0; n < 4; ++n)
                    acc[m][n] = __builtin_amdgcn_mfma_f32_16x16x32_bf16(
                        af[m], bw[n], acc[m][n], 0, 0, 0);
        }
    }

    // epilogue: cross-wave combine sent x gate, maxpool
    const int c0 = cb * 128;
    const int cl = t & 127, rh = t >> 7;
    const float bs = ctx_b[c0 + cl];
    const float bg = gate_b[c0 + cl];
    float pm = -1e30f;
    for (int ms = 0; ms < 8; ++ms) {
        __syncthreads();
        #pragma unroll
        for (int n = 0; n < 4; ++n) {
            int col = (wave << 6) + (n << 4) + lane15;
            #pragma unroll
            for (int i2 = 0; i2 < 4; ++i2)
                ep[(lq * 4 + i2) * 256 + col] = acc[ms][n][i2];
        }
        __syncthreads();
        #pragma unroll
        for (int rr = 0; rr < 8; ++rr) {
            int r = rh * 8 + rr;
            float sv = ep[r * 256 + cl] + bs;
            float gv = ep[r * 256 + 128 + cl] + bg;
            pm = fmaxf(pm, tanhf(sv) * fmaxf(gv, 0.f));
        }
    }
    __syncthreads();
    ep[t] = pm;
    __syncthreads();
    if (t < 128)
        part[((size_t)b * 4 + lb) * 256 + c0 + cl] = fmaxf(ep[t], ep[t + 128]);
}

// ---------------- final: max over 4 l-blocks + linear
__global__ __launch_bounds__(256) void finalize(const float* __restrict__ part,
                                                const float* __restrict__ lin_w,
                                                const float* __restrict__ lin_b,
                                                float* __restrict__ out) {
    __shared__ float pl[256];
    __shared__ float red[256];
    int b = blockIdx.x, t = threadIdx.x;
    float p = part[((size_t)b * 4) * 256 + t];
    for (int lb = 1; lb < 4; ++lb)
        p = fmaxf(p, part[((size_t)b * 4 + lb) * 256 + t]);
    pl[t] = p;
    __syncthreads();
    for (int n = 0; n < NCLASS; ++n) {
        red[t] = pl[t] * lin_w[n * NC + t];
        __syncthreads();
        for (int sft = 128; sft > 0; sft >>= 1) {
            if (t < sft) red[t] += red[t + sft];
            __syncthreads();
        }
        if (t == 0) out[b * NCLASS + n] = red[0] + lin_b[n];
        __syncthreads();
    }
}

extern "C" void kernel_launch(void* const* d_in, const int* in_sizes, int n_in,
                              void* d_out, int out_size, void* d_ws, size_t ws_size,
                              hipStream_t stream) {
    const int* cids = (const int*)d_in[0];
    const int* aids = (const int*)d_in[2];
    const float* amask = (const float*)d_in[3];
    const float* wordmat = (const float*)d_in[4];
    const float* Wm = (const float*)d_in[5];
    const float* ctx_w = (const float*)d_in[6];
    const float* ctx_b = (const float*)d_in[7];
    const float* gate_w = (const float*)d_in[8];
    const float* gate_b = (const float*)d_in[9];
    const float* lin_w = (const float*)d_in[10];
    const float* lin_b = (const float*)d_in[11];
    float* out = (float*)d_out;

    float* asp = (float*)d_ws;                                  // 1,228,800 f
    float* sbuf = asp + 1228800;                                // 2,097,152 f
    float* part = sbuf + 2097152;                               // 131,072 f
    __hip_bfloat16* albf = (__hip_bfloat16*)asp;                // alias: asp dead after prep_aspf
    __hip_bfloat16* aspb = (__hip_bfloat16*)(part + 131072);    // 1,310,720 bf16
    __hip_bfloat16* sybf = aspb + 1310720;                      // 1,310,720
    __hip_bfloat16* aspf = sybf + 1310720;                      // 1,245,184
    __hip_bfloat16* Wb = aspf + 1245184;                        // 97,280
    __hip_bfloat16* Wp2 = Wb + WB_ELEMS;                        // 933,888
    __hip_bfloat16* Xc = Wp2 + WP2_ELEMS;                       // 40,001,536

    prep_wp<<<(WP2_ELEMS + 255) / 256, 256, 0, stream>>>(ctx_w, gate_w, Wp2);
    prep_wb<<<(WB_ELEMS + 255) / 256, 256, 0, stream>>>(Wm, Wb);
    gather_rows<<<BB * L2, 256, 0, stream>>>(aids, wordmat, asp, aspb, sybf);
    prep_aspf<<<(BB * 19 * 512 + 255) / 256, 256, 0, stream>>>(asp, aspf);
    xcat_x<<<BB * L1 / 8, 256, 0, stream>>>(cids, wordmat, Xc);
    sy_mfma<<<(BB * L2) / 64, 256, 0, stream>>>(aspb, Wb, sybf);
    sxs_mfma<<<dim3(L1 / 64, BB), 256, 0, stream>>>(Xc, Wb, sybf, sbuf);
    softmax_col<<<dim3(BB, 2), 256, 0, stream>>>(sbuf, amask, albf);
    att_mfma<<<dim3(L1 / 64, BB), 256, 0, stream>>>(albf, aspf, Xc);
    conv_mfma<<<dim3(8, BB), 256, 0, stream>>>(Xc, Wp2, ctx_b, gate_b, part);
    finalize<<<BB, 256, 0, stream>>>(part, lin_w, lin_b, out);
}

// Round 5
// 225.394 us; speedup vs baseline: 14.9884x; 1.3776x over previous
//
#include <hip/hip_runtime.h>
#include <hip/hip_bf16.h>
#include <math.h>
#include <stdint.h>

#define DIM 300
#define NC 256
#define KS 3
#define NCLASS 3
#define BB 128
#define L1 512
#define L2 32

#define XW 608            // Xc row: [emb 0..299 | 0 300..303 | att 304..603 | 0 604..607]
#define XROWS 514         // guard row + 512 + guard row, per batch
#define ROW_B (XW * 2)    // 1216 bytes
#define NKC 19
#define WP2_ELEMS (2 * 4 * 19 * 3 * 4 * 64 * 8)   // 933,888
#define WB_ELEMS (10 * 19 * 64 * 8)               // 97,280
#define WAVE_WP_B (19 * 3 * 4 * 1024)             // 233,472 B per (cb,role)

#define ABUF_B 8448       // one A double-buffer half (130 rows x 64B, padded)
#define EP_LD 260         // padded epilogue stride (floats)

typedef __attribute__((ext_vector_type(8))) short bf16x8;
typedef __attribute__((ext_vector_type(4))) short bf16x4;
typedef __attribute__((ext_vector_type(4))) float f32x4;

#define GLOBAL_AS __attribute__((address_space(1)))
#define LDS_AS __attribute__((address_space(3)))

__device__ __forceinline__ void gload_lds16(const void* g, void* l) {
    __builtin_amdgcn_global_load_lds((const GLOBAL_AS void*)g, (LDS_AS void*)l, 16, 0, 0);
}

static __device__ __forceinline__ short bfr(float x) {
    __hip_bfloat16 h = __float2bfloat16(x);
    return *(short*)&h;
}

// ---------------- conv weight pre-pack: Wp2[cb][role][kc][tap][n][lane][8]
__global__ void prep_wp(const float* __restrict__ ctx_w,
                        const float* __restrict__ gate_w,
                        __hip_bfloat16* __restrict__ Wp2) {
    int idx = blockIdx.x * 256 + threadIdx.x;
    if (idx >= WP2_ELEMS) return;
    int jj = idx & 7;
    int lane = (idx >> 3) & 63;
    int n = (idx >> 9) & 3;
    int rest = idx >> 11;
    int tap = rest % 3;
    int r2 = rest / 3;
    int kc = r2 % 19;
    int w = r2 / 19;
    int wave = w & 3, cbv = w >> 2;
    int k = kc * 32 + ((lane >> 4) << 3) + jj;
    int nl = wave * 64 + n * 16 + (lane & 15);
    float v = 0.f;
    if (nl < 128) {                    // sentiment channels
        int ch = cbv * 128 + nl;
        if (k < 300) v = ctx_w[(ch * DIM + k) * KS + tap];
    } else {                           // gate channels
        int ch = cbv * 128 + (nl - 128);
        if (k < 300) v = gate_w[(ch * 2 * DIM + k) * KS + tap];
        else if (k >= 304 && k < 604) v = gate_w[(ch * 2 * DIM + (k - 4)) * KS + tap];
    }
    Wp2[idx] = __float2bfloat16(v);
}

// ---------------- W pre-pack for sx/sy GEMMs (zero-padded)
__global__ void prep_wb(const float* __restrict__ Wm,
                        __hip_bfloat16* __restrict__ Wb) {
    int idx = blockIdx.x * 256 + threadIdx.x;
    if (idx >= WB_ELEMS) return;
    int j = idx & 7;
    int l = (idx >> 3) & 63;
    int r = idx >> 9;
    int nf = r % 19, kc = r / 19;
    int k = kc * 32 + ((l >> 4) << 3) + j;
    int n = nf * 16 + (l & 15);
    float v = (k < 300 && n < 300) ? Wm[k * DIM + n] : 0.f;
    Wb[idx] = __float2bfloat16(v);
}

// ---------------- aspect gather: fp32 + bf16 padded + sy pad zeros
__global__ void gather_rows(const int* __restrict__ ids,
                            const float* __restrict__ wordmat,
                            float* __restrict__ asp,
                            __hip_bfloat16* __restrict__ aspb,
                            __hip_bfloat16* __restrict__ syb) {
    int row = blockIdx.x;
    int id = ids[row];
    const float* src = wordmat + (size_t)id * DIM;
    for (int d = threadIdx.x; d < 320; d += blockDim.x) {
        if (d < DIM) {
            float v = src[d];
            asp[(size_t)row * DIM + d] = v;
            aspb[(size_t)row * 320 + d] = __float2bfloat16(v);
        } else {
            aspb[(size_t)row * 320 + d] = __float2bfloat16(0.f);
            if (d >= 304) syb[(size_t)row * 320 + d] = __float2bfloat16(0.f);
        }
    }
}

// ---------------- aspect B-frag pack for att GEMM: aspf[b][nf][lane][8]
__global__ void prep_aspf(const float* __restrict__ asp,
                          __hip_bfloat16* __restrict__ aspf) {
    int idx = blockIdx.x * 256 + threadIdx.x;
    if (idx >= BB * 19 * 512) return;
    int jj = idx & 7;
    int lane = (idx >> 3) & 63;
    int r = idx >> 9;
    int nf = r % 19, b = r / 19;
    int j = ((lane >> 4) << 3) + jj;
    int col = nf * 16 + (lane & 15);
    float v = (col < 300) ? asp[((size_t)b * L2 + j) * DIM + col] : 0.f;
    aspf[idx] = __float2bfloat16(v);
}

// ---------------- Xcat x-part: vectorized bf16 gather + pad + guard rows
__global__ __launch_bounds__(256) void xcat_x(const int* __restrict__ cids,
                                              const float* __restrict__ wordmat,
                                              __hip_bfloat16* __restrict__ Xc) {
    int t = threadIdx.x;
    int rloc = t >> 5, lane = t & 31;
    int row = blockIdx.x * 8 + rloc;          // 0..65535
    int b = row >> 9, l = row & 511;
    size_t id = (size_t)cids[row];
    const float4* src = (const float4*)(wordmat + id * DIM);
    __hip_bfloat16* dst = Xc + ((size_t)b * XROWS + 1 + l) * XW;
    #pragma unroll
    for (int c = lane; c < 76; c += 32) {
        bf16x4 o;
        if (c < 75) {
            float4 f = src[c];
            o[0] = bfr(f.x); o[1] = bfr(f.y); o[2] = bfr(f.z); o[3] = bfr(f.w);
        } else {
            o = (bf16x4)0;   // cols 300..303
        }
        ((bf16x4*)dst)[c] = o;
    }
    // zero guard rows (256 of them), 1216B each via 8B stores
    if (blockIdx.x < 256 && t < 152) {
        int b2 = blockIdx.x >> 1;
        int gr = (blockIdx.x & 1) ? (XROWS - 1) : 0;
        ((bf16x4*)(Xc + ((size_t)b2 * XROWS + gr) * XW))[t] = (bf16x4)0;
    }
}

// ---------------- sy = relu(aspect @ W) via MFMA, direct-from-global
__global__ __launch_bounds__(256, 2) void sy_mfma(
        const __hip_bfloat16* __restrict__ aspb,
        const __hip_bfloat16* __restrict__ Wb,
        __hip_bfloat16* __restrict__ syb) {
    const int t = threadIdx.x, wave = t >> 6, l = t & 63;
    const int lane15 = l & 15, lq = l >> 4;
    const int g = blockIdx.x * 64 + wave * 16 + lane15;
    f32x4 acc[19];
    #pragma unroll
    for (int nf = 0; nf < 19; ++nf) acc[nf] = (f32x4)0.f;
    const bf16x8* Arow = (const bf16x8*)((const char*)aspb + (size_t)g * 640);
    const bf16x8* WbV = (const bf16x8*)Wb;
    for (int kc = 0; kc < 10; ++kc) {
        bf16x8 af = Arow[kc * 4 + lq];
        #pragma unroll
        for (int nf = 0; nf < 19; ++nf)
            acc[nf] = __builtin_amdgcn_mfma_f32_16x16x32_bf16(
                af, WbV[(kc * 19 + nf) * 64 + l], acc[nf], 0, 0, 0);
    }
    #pragma unroll
    for (int nf = 0; nf < 19; ++nf) {
        int col = nf * 16 + lane15;
        #pragma unroll
        for (int i2 = 0; i2 < 4; ++i2) {
            int row = blockIdx.x * 64 + wave * 16 + lq * 4 + i2;
            syb[(size_t)row * 320 + col] = __float2bfloat16(fmaxf(acc[nf][i2], 0.f));
        }
    }
}

// ---------------- fused sx+s (guard-row layout), no syncthreads
__global__ __launch_bounds__(256, 2) void sxs_mfma(
        const __hip_bfloat16* __restrict__ Xc,
        const __hip_bfloat16* __restrict__ Wb,
        const __hip_bfloat16* __restrict__ syb,
        float* __restrict__ s) {
    __shared__ __align__(16) char sxL[4 * 16 * 640];  // 40KB, wave-private
    const int t = threadIdx.x, wave = t >> 6, l = t & 63;
    const int lane15 = l & 15, lq = l >> 4;
    const int lb = blockIdx.x, b = blockIdx.y;
    const int g = b * XROWS + 1 + lb * 64 + wave * 16 + lane15;

    f32x4 acc[19];
    #pragma unroll
    for (int nf = 0; nf < 19; ++nf) acc[nf] = (f32x4)0.f;

    const bf16x8* Arow = (const bf16x8*)((const char*)Xc + (size_t)g * ROW_B);
    const bf16x8* WbV = (const bf16x8*)Wb;
    for (int kc = 0; kc < 10; ++kc) {
        bf16x8 af = Arow[kc * 4 + lq];
        #pragma unroll
        for (int nf = 0; nf < 19; ++nf)
            acc[nf] = __builtin_amdgcn_mfma_f32_16x16x32_bf16(
                af, WbV[(kc * 19 + nf) * 64 + l], acc[nf], 0, 0, 0);
    }

    char* sxW = sxL + wave * (16 * 640);
    if (l < 32) {
        int row = l >> 1;
        int phys = (2 + (l & 1)) ^ ((row >> 2) & 3);
        *(f32x4*)(sxW + row * 640 + 576 + phys * 16) = (f32x4)0.f;
    }
    #pragma unroll
    for (int nf = 0; nf < 19; ++nf) {
        int col = nf * 16 + lane15;
        #pragma unroll
        for (int i2 = 0; i2 < 4; ++i2) {
            int row = lq * 4 + i2;
            int off = row * 640 + ((col >> 5) << 6) +
                      ((((col >> 3) & 3) ^ ((row >> 2) & 3)) << 4) + ((col & 7) << 1);
            *(__hip_bfloat16*)(sxW + off) = __float2bfloat16(fmaxf(acc[nf][i2], 0.f));
        }
    }
    f32x4 acc2[2];
    acc2[0] = (f32x4)0.f;
    acc2[1] = (f32x4)0.f;
    const bf16x8* syV = (const bf16x8*)syb + (size_t)b * 32 * 40;
    for (int kc = 0; kc < 10; ++kc) {
        bf16x8 af2 = *(const bf16x8*)(sxW + lane15 * 640 + kc * 64 +
                                      ((lq ^ ((lane15 >> 2) & 3)) << 4));
        #pragma unroll
        for (int nj = 0; nj < 2; ++nj) {
            bf16x8 bfj = syV[(nj * 16 + lane15) * 40 + kc * 4 + lq];
            acc2[nj] = __builtin_amdgcn_mfma_f32_16x16x32_bf16(af2, bfj, acc2[nj], 0, 0, 0);
        }
    }
    #pragma unroll
    for (int nj = 0; nj < 2; ++nj)
        #pragma unroll
        for (int i2 = 0; i2 < 4; ++i2) {
            int i = lb * 64 + wave * 16 + lq * 4 + i2;
            s[((size_t)b * L1 + i) * L2 + nj * 16 + lane15] = acc2[nj][i2];
        }
}

// ---------------- softmax over dim=1 (L1): single-read, bf16 alpha out
__global__ __launch_bounds__(256) void softmax_col(const float* __restrict__ s,
                                                   const float* __restrict__ amask,
                                                   __hip_bfloat16* __restrict__ albf) {
    __shared__ float red[256];
    __shared__ float cmax[16], cscale[16];
    int b = blockIdx.x, jh = blockIdx.y, t = threadIdx.x;
    int jl = t & 15, j = jh * 16 + jl, ii = t >> 4;
    const float* sb = s + (size_t)b * L1 * L2;
    float v[32];
    float m = -1e30f;
    #pragma unroll
    for (int q = 0; q < 32; ++q) {
        v[q] = sb[(size_t)(ii + q * 16) * L2 + j];
        m = fmaxf(m, v[q]);
    }
    red[t] = m;
    __syncthreads();
    if (t < 16) {
        float mm = red[t];
        for (int p = 1; p < 16; ++p) mm = fmaxf(mm, red[p * 16 + t]);
        cmax[t] = mm;
    }
    __syncthreads();
    float cm = cmax[jl];
    float sum = 0.f;
    #pragma unroll
    for (int q = 0; q < 32; ++q) {
        v[q] = expf(v[q] - cm);
        sum += v[q];
    }
    red[t] = sum;
    __syncthreads();
    if (t < 16) {
        float ss = 0.f;
        for (int p = 0; p < 16; ++p) ss += red[p * 16 + t];
        float mk = amask[b * L2 + jh * 16 + t];
        cscale[t] = mk / (mk * ss + 1e-10f);
    }
    __syncthreads();
    float sc = cscale[jl];
    #pragma unroll
    for (int q = 0; q < 32; ++q)
        albf[(size_t)(b * L1 + ii + q * 16) * L2 + j] = __float2bfloat16(v[q] * sc);
}

// ---------------- att = alpha @ aspect via MFMA (K=32 single chunk) -> Xc[304..607]
__global__ __launch_bounds__(256, 2) void att_mfma(
        const __hip_bfloat16* __restrict__ albf,
        const __hip_bfloat16* __restrict__ aspf,
        __hip_bfloat16* __restrict__ Xc) {
    __shared__ __align__(16) __hip_bfloat16 tl[4][16][320];  // 40KB, wave-private
    const int t = threadIdx.x, wave = t >> 6, l = t & 63;
    const int lane15 = l & 15, lq = l >> 4;
    const int ax = blockIdx.x, b = blockIdx.y;
    const int row = ax * 64 + wave * 16 + lane15;

    bf16x8 af = *(const bf16x8*)(albf + ((size_t)b * L1 + row) * L2 + lq * 8);
    f32x4 acc[19];
    #pragma unroll
    for (int nf = 0; nf < 19; ++nf) acc[nf] = (f32x4)0.f;
    const bf16x8* bp = (const bf16x8*)aspf + (size_t)b * 19 * 64;
    #pragma unroll
    for (int nf = 0; nf < 19; ++nf)
        acc[nf] = __builtin_amdgcn_mfma_f32_16x16x32_bf16(af, bp[nf * 64 + l], acc[nf], 0, 0, 0);

    #pragma unroll
    for (int nf = 0; nf < 19; ++nf) {
        int col = nf * 16 + lane15;
        #pragma unroll
        for (int i2 = 0; i2 < 4; ++i2)
            tl[wave][lq * 4 + i2][col] = __float2bfloat16(acc[nf][i2]);
    }
    // wave-private transpose -> coalesced 16B stores at col 304
    for (int r = 0; r < 16; ++r) {
        if (l < 38) {
            bf16x8 vv = *(const bf16x8*)&tl[wave][r][l * 8];
            *(bf16x8*)(Xc + ((size_t)b * XROWS + 1 + ax * 64 + wave * 16 + r) * XW + 304 + l * 8) = vv;
        }
    }
}

// ---------------- conv GEMM v3: A double-buffered in LDS (global_load_lds),
// B direct-from-global (L2-resident), one barrier per kc (drain ~free since
// B-loads issued after stage ops are consumed by MFMAs -> in-order completion
// guarantees stage done). Wave roles XOR'd by block parity to balance the
// sentiment(30 K-steps)/gate(57 K-steps) imbalance across co-resident blocks.
__global__ __launch_bounds__(256, 2) void conv_mfma(
        const __hip_bfloat16* __restrict__ Xc,
        const __hip_bfloat16* __restrict__ Wp2,
        const float* __restrict__ ctx_b,
        const float* __restrict__ gate_b,
        float* __restrict__ part) {
    __shared__ __align__(16) char lds[2 * ABUF_B];   // 16.9KB; epilogue aliases
    const int t = threadIdx.x, wave = t >> 6, lane = t & 63;
    const int lane15 = lane & 15, lq = lane >> 4;
    const int lb = blockIdx.x >> 1, cb = blockIdx.x & 1;
    const int b = blockIdx.y, l0 = lb * 128;
    const int role = wave ^ ((blockIdx.x & 1) << 1);

    f32x4 acc[8][4];
    #pragma unroll
    for (int m = 0; m < 8; ++m)
        #pragma unroll
        for (int n = 0; n < 4; ++n) acc[m][n] = (f32x4)0.f;

    const char* XcB = (const char*)Xc + (size_t)b * XROWS * ROW_B + (size_t)l0 * ROW_B;
    const char* bbase = (const char*)Wp2 + (size_t)(cb * 4 + role) * WAVE_WP_B + lane * 16;
    const int kcEnd = (role < 2) ? 10 : 19;

    // stage A-tile for kc into buf: 130 rows x 64B, source pre-swizzled (rule #21)
    #define STAGE_A(kc_, buf_) do {                                              \
        char* Ab_ = lds + (buf_) * ABUF_B;                                       \
        _Pragma("unroll")                                                        \
        for (int i = 0; i < 3; ++i) {                                            \
            int chunk = (i * 4 + wave) * 64 + lane;                              \
            if (chunk < 520) {                                                   \
                int row_ = chunk >> 2, c_ = chunk & 3;                           \
                int sc_ = (c_ ^ (row_ & 3)) << 4;                                \
                gload_lds16(XcB + (size_t)row_ * ROW_B + (kc_) * 64 + sc_,       \
                            Ab_ + (i * 4 + wave) * 1024);                        \
            }                                                                    \
        }                                                                        \
    } while (0)

    STAGE_A(0, 0);
    __syncthreads();

    for (int kc = 0; kc < NKC; ++kc) {
        const int cbuf = kc & 1;
        if (kc < NKC - 1) STAGE_A(kc + 1, cbuf ^ 1);
        if (kc < kcEnd) {
            const char* Ab = lds + cbuf * ABUF_B;
            #pragma unroll
            for (int tap = 0; tap < 3; ++tap) {
                bf16x8 bw[4];
                #pragma unroll
                for (int n = 0; n < 4; ++n)
                    bw[n] = *(const bf16x8*)(bbase +
                            (size_t)((kc * 3 + tap) * 4 + n) * 1024);
                bf16x8 af[8];
                #pragma unroll
                for (int m = 0; m < 8; ++m) {
                    int row = m * 16 + lane15 + tap;
                    af[m] = *(const bf16x8*)(Ab + row * 64 +
                                             ((lq ^ (row & 3)) << 4));
                }
                #pragma unroll
                for (int m = 0; m < 8; ++m)
                    #pragma unroll
                    for (int n = 0; n < 4; ++n)
                        acc[m][n] = __builtin_amdgcn_mfma_f32_16x16x32_bf16(
                            af[m], bw[n], acc[m][n], 0, 0, 0);
            }
        }
        __syncthreads();
    }
    #undef STAGE_A

    // epilogue: cross-wave combine sent x gate, maxpool (padded stride EP_LD)
    const int c0 = cb * 128;
    const int cl = t & 127, rh = t >> 7;
    const float bs = ctx_b[c0 + cl];
    const float bg = gate_b[c0 + cl];
    float* ep = (float*)lds;   // 16 x EP_LD floats = 16.6KB (fits 2*ABUF_B)
    float pm = -1e30f;
    for (int ms = 0; ms < 8; ++ms) {
        __syncthreads();
        #pragma unroll
        for (int n = 0; n < 4; ++n) {
            int col = (role << 6) + (n << 4) + lane15;
            #pragma unroll
            for (int i2 = 0; i2 < 4; ++i2)
                ep[(lq * 4 + i2) * EP_LD + col] = acc[ms][n][i2];
        }
        __syncthreads();
        #pragma unroll
        for (int rr = 0; rr < 8; ++rr) {
            int r = rh * 8 + rr;
            float sv = ep[r * EP_LD + cl] + bs;
            float gv = ep[r * EP_LD + 128 + cl] + bg;
            pm = fmaxf(pm, tanhf(sv) * fmaxf(gv, 0.f));
        }
    }
    __syncthreads();
    ep[t] = pm;
    __syncthreads();
    if (t < 128)
        part[((size_t)b * 4 + lb) * 256 + c0 + cl] = fmaxf(ep[t], ep[t + 128]);
}

// ---------------- final: max over 4 l-blocks + linear
__global__ __launch_bounds__(256) void finalize(const float* __restrict__ part,
                                                const float* __restrict__ lin_w,
                                                const float* __restrict__ lin_b,
                                                float* __restrict__ out) {
    __shared__ float pl[256];
    __shared__ float red[256];
    int b = blockIdx.x, t = threadIdx.x;
    float p = part[((size_t)b * 4) * 256 + t];
    for (int lb = 1; lb < 4; ++lb)
        p = fmaxf(p, part[((size_t)b * 4 + lb) * 256 + t]);
    pl[t] = p;
    __syncthreads();
    for (int n = 0; n < NCLASS; ++n) {
        red[t] = pl[t] * lin_w[n * NC + t];
        __syncthreads();
        for (int sft = 128; sft > 0; sft >>= 1) {
            if (t < sft) red[t] += red[t + sft];
            __syncthreads();
        }
        if (t == 0) out[b * NCLASS + n] = red[0] + lin_b[n];
        __syncthreads();
    }
}

extern "C" void kernel_launch(void* const* d_in, const int* in_sizes, int n_in,
                              void* d_out, int out_size, void* d_ws, size_t ws_size,
                              hipStream_t stream) {
    const int* cids = (const int*)d_in[0];
    const int* aids = (const int*)d_in[2];
    const float* amask = (const float*)d_in[3];
    const float* wordmat = (const float*)d_in[4];
    const float* Wm = (const float*)d_in[5];
    const float* ctx_w = (const float*)d_in[6];
    const float* ctx_b = (const float*)d_in[7];
    const float* gate_w = (const float*)d_in[8];
    const float* gate_b = (const float*)d_in[9];
    const float* lin_w = (const float*)d_in[10];
    const float* lin_b = (const float*)d_in[11];
    float* out = (float*)d_out;

    float* asp = (float*)d_ws;                                  // 1,228,800 f
    float* sbuf = asp + 1228800;                                // 2,097,152 f
    float* part = sbuf + 2097152;                               // 131,072 f
    __hip_bfloat16* albf = (__hip_bfloat16*)asp;                // alias: asp dead after prep_aspf
    __hip_bfloat16* aspb = (__hip_bfloat16*)(part + 131072);    // 1,310,720 bf16
    __hip_bfloat16* sybf = aspb + 1310720;                      // 1,310,720
    __hip_bfloat16* aspf = sybf + 1310720;                      // 1,245,184
    __hip_bfloat16* Wb = aspf + 1245184;                        // 97,280
    __hip_bfloat16* Wp2 = Wb + WB_ELEMS;                        // 933,888
    __hip_bfloat16* Xc = Wp2 + WP2_ELEMS;                       // 40,001,536

    prep_wp<<<(WP2_ELEMS + 255) / 256, 256, 0, stream>>>(ctx_w, gate_w, Wp2);
    prep_wb<<<(WB_ELEMS + 255) / 256, 256, 0, stream>>>(Wm, Wb);
    gather_rows<<<BB * L2, 256, 0, stream>>>(aids, wordmat, asp, aspb, sybf);
    prep_aspf<<<(BB * 19 * 512 + 255) / 256, 256, 0, stream>>>(asp, aspf);
    xcat_x<<<BB * L1 / 8, 256, 0, stream>>>(cids, wordmat, Xc);
    sy_mfma<<<(BB * L2) / 64, 256, 0, stream>>>(aspb, Wb, sybf);
    sxs_mfma<<<dim3(L1 / 64, BB), 256, 0, stream>>>(Xc, Wb, sybf, sbuf);
    softmax_col<<<dim3(BB, 2), 256, 0, stream>>>(sbuf, amask, albf);
    att_mfma<<<dim3(L1 / 64, BB), 256, 0, stream>>>(albf, aspf, Xc);
    conv_mfma<<<dim3(8, BB), 256, 0, stream>>>(Xc, Wp2, ctx_b, gate_b, part);
    finalize<<<BB, 256, 0, stream>>>(part, lin_w, lin_b, out);
}

// Round 6
// 216.095 us; speedup vs baseline: 15.6334x; 1.0430x over previous
//
#include <hip/hip_runtime.h>
#include <hip/hip_bf16.h>
#include <math.h>
#include <stdint.h>

#define DIM 300
#define NC 256
#define KS 3
#define NCLASS 3
#define BB 128
#define L1 512
#define L2 32

#define XW 608            // Xc row: [emb 0..299 | 0 300..303 | att 304..603 | 0 604..607]
#define XROWS 514         // guard row + 512 + guard row, per batch
#define ROW_B (XW * 2)    // 1216 bytes
#define NKC 19
#define WP2_ELEMS (2 * 4 * 19 * 3 * 4 * 64 * 8)   // 933,888
#define WB_ELEMS (10 * 19 * 64 * 8)               // 97,280
#define WAVE_WP_B (19 * 3 * 4 * 1024)             // 233,472 B per (cb,role)

#define ABUF_B 4224       // one A double-buffer half (66 rows x 64B)
#define EP_LD 260         // padded epilogue stride (floats)

typedef __attribute__((ext_vector_type(8))) short bf16x8;
typedef __attribute__((ext_vector_type(4))) short bf16x4;
typedef __attribute__((ext_vector_type(4))) float f32x4;

#define GLOBAL_AS __attribute__((address_space(1)))
#define LDS_AS __attribute__((address_space(3)))

__device__ __forceinline__ void gload_lds16(const void* g, void* l) {
    __builtin_amdgcn_global_load_lds((const GLOBAL_AS void*)g, (LDS_AS void*)l, 16, 0, 0);
}

static __device__ __forceinline__ short bfr(float x) {
    __hip_bfloat16 h = __float2bfloat16(x);
    return *(short*)&h;
}

// ---------------- conv weight pre-pack: Wp2[cb][role][kc][tap][n][lane][8]
__global__ void prep_wp(const float* __restrict__ ctx_w,
                        const float* __restrict__ gate_w,
                        __hip_bfloat16* __restrict__ Wp2) {
    int idx = blockIdx.x * 256 + threadIdx.x;
    if (idx >= WP2_ELEMS) return;
    int jj = idx & 7;
    int lane = (idx >> 3) & 63;
    int n = (idx >> 9) & 3;
    int rest = idx >> 11;
    int tap = rest % 3;
    int r2 = rest / 3;
    int kc = r2 % 19;
    int w = r2 / 19;
    int wave = w & 3, cbv = w >> 2;
    int k = kc * 32 + ((lane >> 4) << 3) + jj;
    int nl = wave * 64 + n * 16 + (lane & 15);
    float v = 0.f;
    if (nl < 128) {                    // sentiment channels
        int ch = cbv * 128 + nl;
        if (k < 300) v = ctx_w[(ch * DIM + k) * KS + tap];
    } else {                           // gate channels
        int ch = cbv * 128 + (nl - 128);
        if (k < 300) v = gate_w[(ch * 2 * DIM + k) * KS + tap];
        else if (k >= 304 && k < 604) v = gate_w[(ch * 2 * DIM + (k - 4)) * KS + tap];
    }
    Wp2[idx] = __float2bfloat16(v);
}

// ---------------- W pre-pack for sx/sy GEMMs (zero-padded)
__global__ void prep_wb(const float* __restrict__ Wm,
                        __hip_bfloat16* __restrict__ Wb) {
    int idx = blockIdx.x * 256 + threadIdx.x;
    if (idx >= WB_ELEMS) return;
    int j = idx & 7;
    int l = (idx >> 3) & 63;
    int r = idx >> 9;
    int nf = r % 19, kc = r / 19;
    int k = kc * 32 + ((l >> 4) << 3) + j;
    int n = nf * 16 + (l & 15);
    float v = (k < 300 && n < 300) ? Wm[k * DIM + n] : 0.f;
    Wb[idx] = __float2bfloat16(v);
}

// ---------------- aspect gather: fp32 + bf16 padded + sy pad zeros
__global__ void gather_rows(const int* __restrict__ ids,
                            const float* __restrict__ wordmat,
                            float* __restrict__ asp,
                            __hip_bfloat16* __restrict__ aspb,
                            __hip_bfloat16* __restrict__ syb) {
    int row = blockIdx.x;
    int id = ids[row];
    const float* src = wordmat + (size_t)id * DIM;
    for (int d = threadIdx.x; d < 320; d += blockDim.x) {
        if (d < DIM) {
            float v = src[d];
            asp[(size_t)row * DIM + d] = v;
            aspb[(size_t)row * 320 + d] = __float2bfloat16(v);
        } else {
            aspb[(size_t)row * 320 + d] = __float2bfloat16(0.f);
            if (d >= 304) syb[(size_t)row * 320 + d] = __float2bfloat16(0.f);
        }
    }
}

// ---------------- aspect B-frag pack for att GEMM: aspf[b][nf][lane][8]
__global__ void prep_aspf(const float* __restrict__ asp,
                          __hip_bfloat16* __restrict__ aspf) {
    int idx = blockIdx.x * 256 + threadIdx.x;
    if (idx >= BB * 19 * 512) return;
    int jj = idx & 7;
    int lane = (idx >> 3) & 63;
    int r = idx >> 9;
    int nf = r % 19, b = r / 19;
    int j = ((lane >> 4) << 3) + jj;
    int col = nf * 16 + (lane & 15);
    float v = (col < 300) ? asp[((size_t)b * L2 + j) * DIM + col] : 0.f;
    aspf[idx] = __float2bfloat16(v);
}

// ---------------- Xcat x-part: vectorized bf16 gather + pad + guard rows
__global__ __launch_bounds__(256) void xcat_x(const int* __restrict__ cids,
                                              const float* __restrict__ wordmat,
                                              __hip_bfloat16* __restrict__ Xc) {
    int t = threadIdx.x;
    int rloc = t >> 5, lane = t & 31;
    int row = blockIdx.x * 8 + rloc;          // 0..65535
    int b = row >> 9, l = row & 511;
    size_t id = (size_t)cids[row];
    const float4* src = (const float4*)(wordmat + id * DIM);
    __hip_bfloat16* dst = Xc + ((size_t)b * XROWS + 1 + l) * XW;
    #pragma unroll
    for (int c = lane; c < 76; c += 32) {
        bf16x4 o;
        if (c < 75) {
            float4 f = src[c];
            o[0] = bfr(f.x); o[1] = bfr(f.y); o[2] = bfr(f.z); o[3] = bfr(f.w);
        } else {
            o = (bf16x4)0;   // cols 300..303
        }
        ((bf16x4*)dst)[c] = o;
    }
    // zero guard rows (256 of them), 1216B each via 8B stores
    if (blockIdx.x < 256 && t < 152) {
        int b2 = blockIdx.x >> 1;
        int gr = (blockIdx.x & 1) ? (XROWS - 1) : 0;
        ((bf16x4*)(Xc + ((size_t)b2 * XROWS + gr) * XW))[t] = (bf16x4)0;
    }
}

// ---------------- sy = relu(aspect @ W) via MFMA, direct-from-global
__global__ __launch_bounds__(256, 2) void sy_mfma(
        const __hip_bfloat16* __restrict__ aspb,
        const __hip_bfloat16* __restrict__ Wb,
        __hip_bfloat16* __restrict__ syb) {
    const int t = threadIdx.x, wave = t >> 6, l = t & 63;
    const int lane15 = l & 15, lq = l >> 4;
    const int g = blockIdx.x * 64 + wave * 16 + lane15;
    f32x4 acc[19];
    #pragma unroll
    for (int nf = 0; nf < 19; ++nf) acc[nf] = (f32x4)0.f;
    const bf16x8* Arow = (const bf16x8*)((const char*)aspb + (size_t)g * 640);
    const bf16x8* WbV = (const bf16x8*)Wb;
    for (int kc = 0; kc < 10; ++kc) {
        bf16x8 af = Arow[kc * 4 + lq];
        #pragma unroll
        for (int nf = 0; nf < 19; ++nf)
            acc[nf] = __builtin_amdgcn_mfma_f32_16x16x32_bf16(
                af, WbV[(kc * 19 + nf) * 64 + l], acc[nf], 0, 0, 0);
    }
    #pragma unroll
    for (int nf = 0; nf < 19; ++nf) {
        int col = nf * 16 + lane15;
        #pragma unroll
        for (int i2 = 0; i2 < 4; ++i2) {
            int row = blockIdx.x * 64 + wave * 16 + lq * 4 + i2;
            syb[(size_t)row * 320 + col] = __float2bfloat16(fmaxf(acc[nf][i2], 0.f));
        }
    }
}

// ---------------- fused sx+s (guard-row layout), no syncthreads
__global__ __launch_bounds__(256, 2) void sxs_mfma(
        const __hip_bfloat16* __restrict__ Xc,
        const __hip_bfloat16* __restrict__ Wb,
        const __hip_bfloat16* __restrict__ syb,
        float* __restrict__ s) {
    __shared__ __align__(16) char sxL[4 * 16 * 640];  // 40KB, wave-private
    const int t = threadIdx.x, wave = t >> 6, l = t & 63;
    const int lane15 = l & 15, lq = l >> 4;
    const int lb = blockIdx.x, b = blockIdx.y;
    const int g = b * XROWS + 1 + lb * 64 + wave * 16 + lane15;

    f32x4 acc[19];
    #pragma unroll
    for (int nf = 0; nf < 19; ++nf) acc[nf] = (f32x4)0.f;

    const bf16x8* Arow = (const bf16x8*)((const char*)Xc + (size_t)g * ROW_B);
    const bf16x8* WbV = (const bf16x8*)Wb;
    for (int kc = 0; kc < 10; ++kc) {
        bf16x8 af = Arow[kc * 4 + lq];
        #pragma unroll
        for (int nf = 0; nf < 19; ++nf)
            acc[nf] = __builtin_amdgcn_mfma_f32_16x16x32_bf16(
                af, WbV[(kc * 19 + nf) * 64 + l], acc[nf], 0, 0, 0);
    }

    char* sxW = sxL + wave * (16 * 640);
    if (l < 32) {
        int row = l >> 1;
        int phys = (2 + (l & 1)) ^ ((row >> 2) & 3);
        *(f32x4*)(sxW + row * 640 + 576 + phys * 16) = (f32x4)0.f;
    }
    #pragma unroll
    for (int nf = 0; nf < 19; ++nf) {
        int col = nf * 16 + lane15;
        #pragma unroll
        for (int i2 = 0; i2 < 4; ++i2) {
            int row = lq * 4 + i2;
            int off = row * 640 + ((col >> 5) << 6) +
                      ((((col >> 3) & 3) ^ ((row >> 2) & 3)) << 4) + ((col & 7) << 1);
            *(__hip_bfloat16*)(sxW + off) = __float2bfloat16(fmaxf(acc[nf][i2], 0.f));
        }
    }
    f32x4 acc2[2];
    acc2[0] = (f32x4)0.f;
    acc2[1] = (f32x4)0.f;
    const bf16x8* syV = (const bf16x8*)syb + (size_t)b * 32 * 40;
    for (int kc = 0; kc < 10; ++kc) {
        bf16x8 af2 = *(const bf16x8*)(sxW + lane15 * 640 + kc * 64 +
                                      ((lq ^ ((lane15 >> 2) & 3)) << 4));
        #pragma unroll
        for (int nj = 0; nj < 2; ++nj) {
            bf16x8 bfj = syV[(nj * 16 + lane15) * 40 + kc * 4 + lq];
            acc2[nj] = __builtin_amdgcn_mfma_f32_16x16x32_bf16(af2, bfj, acc2[nj], 0, 0, 0);
        }
    }
    #pragma unroll
    for (int nj = 0; nj < 2; ++nj)
        #pragma unroll
        for (int i2 = 0; i2 < 4; ++i2) {
            int i = lb * 64 + wave * 16 + lq * 4 + i2;
            s[((size_t)b * L1 + i) * L2 + nj * 16 + lane15] = acc2[nj][i2];
        }
}

// ---------------- softmax over dim=1 (L1): single-read, bf16 alpha out
__global__ __launch_bounds__(256) void softmax_col(const float* __restrict__ s,
                                                   const float* __restrict__ amask,
                                                   __hip_bfloat16* __restrict__ albf) {
    __shared__ float red[256];
    __shared__ float cmax[16], cscale[16];
    int b = blockIdx.x, jh = blockIdx.y, t = threadIdx.x;
    int jl = t & 15, j = jh * 16 + jl, ii = t >> 4;
    const float* sb = s + (size_t)b * L1 * L2;
    float v[32];
    float m = -1e30f;
    #pragma unroll
    for (int q = 0; q < 32; ++q) {
        v[q] = sb[(size_t)(ii + q * 16) * L2 + j];
        m = fmaxf(m, v[q]);
    }
    red[t] = m;
    __syncthreads();
    if (t < 16) {
        float mm = red[t];
        for (int p = 1; p < 16; ++p) mm = fmaxf(mm, red[p * 16 + t]);
        cmax[t] = mm;
    }
    __syncthreads();
    float cm = cmax[jl];
    float sum = 0.f;
    #pragma unroll
    for (int q = 0; q < 32; ++q) {
        v[q] = expf(v[q] - cm);
        sum += v[q];
    }
    red[t] = sum;
    __syncthreads();
    if (t < 16) {
        float ss = 0.f;
        for (int p = 0; p < 16; ++p) ss += red[p * 16 + t];
        float mk = amask[b * L2 + jh * 16 + t];
        cscale[t] = mk / (mk * ss + 1e-10f);
    }
    __syncthreads();
    float sc = cscale[jl];
    #pragma unroll
    for (int q = 0; q < 32; ++q)
        albf[(size_t)(b * L1 + ii + q * 16) * L2 + j] = __float2bfloat16(v[q] * sc);
}

// ---------------- att = alpha @ aspect via MFMA (K=32 single chunk) -> Xc[304..607]
__global__ __launch_bounds__(256, 2) void att_mfma(
        const __hip_bfloat16* __restrict__ albf,
        const __hip_bfloat16* __restrict__ aspf,
        __hip_bfloat16* __restrict__ Xc) {
    __shared__ __align__(16) __hip_bfloat16 tl[4][16][320];  // 40KB, wave-private
    const int t = threadIdx.x, wave = t >> 6, l = t & 63;
    const int lane15 = l & 15, lq = l >> 4;
    const int ax = blockIdx.x, b = blockIdx.y;
    const int row = ax * 64 + wave * 16 + lane15;

    bf16x8 af = *(const bf16x8*)(albf + ((size_t)b * L1 + row) * L2 + lq * 8);
    f32x4 acc[19];
    #pragma unroll
    for (int nf = 0; nf < 19; ++nf) acc[nf] = (f32x4)0.f;
    const bf16x8* bp = (const bf16x8*)aspf + (size_t)b * 19 * 64;
    #pragma unroll
    for (int nf = 0; nf < 19; ++nf)
        acc[nf] = __builtin_amdgcn_mfma_f32_16x16x32_bf16(af, bp[nf * 64 + l], acc[nf], 0, 0, 0);

    #pragma unroll
    for (int nf = 0; nf < 19; ++nf) {
        int col = nf * 16 + lane15;
        #pragma unroll
        for (int i2 = 0; i2 < 4; ++i2)
            tl[wave][lq * 4 + i2][col] = __float2bfloat16(acc[nf][i2]);
    }
    // wave-private transpose -> coalesced 16B stores at col 304
    for (int r = 0; r < 16; ++r) {
        if (l < 38) {
            bf16x8 vv = *(const bf16x8*)&tl[wave][r][l * 8];
            *(bf16x8*)(Xc + ((size_t)b * XROWS + 1 + ax * 64 + wave * 16 + r) * XW + 304 + l * 8) = vv;
        }
    }
}

// ---------------- conv GEMM v4: 64-row blocks for occupancy (TLP latency hiding),
// A double-buffered in LDS (global_load_lds, conflict-free (row>>1)&3 swizzle),
// B direct-from-global (L2-resident). Role-XOR balances sent(30)/gate(57 K-steps)
// across co-resident blocks.
__global__ __launch_bounds__(256, 4) void conv_mfma(
        const __hip_bfloat16* __restrict__ Xc,
        const __hip_bfloat16* __restrict__ Wp2,
        const float* __restrict__ ctx_b,
        const float* __restrict__ gate_b,
        float* __restrict__ part) {
    __shared__ __align__(16) char lds[16 * EP_LD * 4];   // 16.6KB; stage aliases front
    const int t = threadIdx.x, wave = t >> 6, lane = t & 63;
    const int lane15 = lane & 15, lq = lane >> 4;
    const int lb = blockIdx.x >> 1, cb = blockIdx.x & 1;
    const int b = blockIdx.y, l0 = lb * 64;
    const int role = wave ^ ((blockIdx.x & 1) << 1);

    f32x4 acc[4][4];
    #pragma unroll
    for (int m = 0; m < 4; ++m)
        #pragma unroll
        for (int n = 0; n < 4; ++n) acc[m][n] = (f32x4)0.f;

    // LDS row r holds global row (b*XROWS + l0 + r), r=0..65  (l0-1..l0+64 logical)
    const char* XcB = (const char*)Xc + ((size_t)b * XROWS + l0) * ROW_B;
    const char* bbase = (const char*)Wp2 + (size_t)(cb * 4 + role) * WAVE_WP_B + lane * 16;
    const int kcEnd = (role < 2) ? 10 : 19;

    // stage A-tile: 66 rows x 64B = 264 chunks; src pre-swizzled with (row>>1)&3
    #define STAGE_A(kc_, buf_) do {                                              \
        char* Ab_ = lds + (buf_) * ABUF_B;                                       \
        _Pragma("unroll")                                                        \
        for (int i = 0; i < 2; ++i) {                                            \
            int chunk = (i * 4 + wave) * 64 + lane;                              \
            if (chunk < 264) {                                                   \
                int row_ = chunk >> 2, c_ = chunk & 3;                           \
                int sc_ = (c_ ^ ((row_ >> 1) & 3)) << 4;                         \
                gload_lds16(XcB + (size_t)row_ * ROW_B + (kc_) * 64 + sc_,       \
                            Ab_ + (i * 4 + wave) * 1024);                        \
            }                                                                    \
        }                                                                        \
    } while (0)

    STAGE_A(0, 0);
    __syncthreads();

    for (int kc = 0; kc < NKC; ++kc) {
        const int cbuf = kc & 1;
        if (kc < NKC - 1) STAGE_A(kc + 1, cbuf ^ 1);
        if (kc < kcEnd) {
            const char* Ab = lds + cbuf * ABUF_B;
            #pragma unroll
            for (int tap = 0; tap < 3; ++tap) {
                bf16x8 bw[4];
                #pragma unroll
                for (int n = 0; n < 4; ++n)
                    bw[n] = *(const bf16x8*)(bbase +
                            (size_t)((kc * 3 + tap) * 4 + n) * 1024);
                bf16x8 af[4];
                #pragma unroll
                for (int m = 0; m < 4; ++m) {
                    int row = m * 16 + lane15 + tap;
                    af[m] = *(const bf16x8*)(Ab + row * 64 +
                                             ((lq ^ ((row >> 1) & 3)) << 4));
                }
                #pragma unroll
                for (int m = 0; m < 4; ++m)
                    #pragma unroll
                    for (int n = 0; n < 4; ++n)
                        acc[m][n] = __builtin_amdgcn_mfma_f32_16x16x32_bf16(
                            af[m], bw[n], acc[m][n], 0, 0, 0);
            }
        }
        __syncthreads();
    }
    #undef STAGE_A

    // epilogue: cross-wave combine sent x gate, maxpool (padded stride EP_LD)
    const int c0 = cb * 128;
    const int cl = t & 127, rh = t >> 7;
    const float bs = ctx_b[c0 + cl];
    const float bg = gate_b[c0 + cl];
    float* ep = (float*)lds;   // 16 x EP_LD floats
    float pm = -1e30f;
    for (int ms = 0; ms < 4; ++ms) {
        __syncthreads();
        #pragma unroll
        for (int n = 0; n < 4; ++n) {
            int col = (role << 6) + (n << 4) + lane15;
            #pragma unroll
            for (int i2 = 0; i2 < 4; ++i2)
                ep[(lq * 4 + i2) * EP_LD + col] = acc[ms][n][i2];
        }
        __syncthreads();
        #pragma unroll
        for (int rr = 0; rr < 8; ++rr) {
            int r = rh * 8 + rr;
            float sv = ep[r * EP_LD + cl] + bs;
            float gv = ep[r * EP_LD + 128 + cl] + bg;
            pm = fmaxf(pm, tanhf(sv) * fmaxf(gv, 0.f));
        }
    }
    __syncthreads();
    ep[t] = pm;
    __syncthreads();
    if (t < 128)
        part[((size_t)b * 8 + lb) * 256 + c0 + cl] = fmaxf(ep[t], ep[t + 128]);
}

// ---------------- final: max over 8 l-blocks + linear
__global__ __launch_bounds__(256) void finalize(const float* __restrict__ part,
                                                const float* __restrict__ lin_w,
                                                const float* __restrict__ lin_b,
                                                float* __restrict__ out) {
    __shared__ float pl[256];
    __shared__ float red[256];
    int b = blockIdx.x, t = threadIdx.x;
    float p = part[((size_t)b * 8) * 256 + t];
    for (int lb = 1; lb < 8; ++lb)
        p = fmaxf(p, part[((size_t)b * 8 + lb) * 256 + t]);
    pl[t] = p;
    __syncthreads();
    for (int n = 0; n < NCLASS; ++n) {
        red[t] = pl[t] * lin_w[n * NC + t];
        __syncthreads();
        for (int sft = 128; sft > 0; sft >>= 1) {
            if (t < sft) red[t] += red[t + sft];
            __syncthreads();
        }
        if (t == 0) out[b * NCLASS + n] = red[0] + lin_b[n];
        __syncthreads();
    }
}

extern "C" void kernel_launch(void* const* d_in, const int* in_sizes, int n_in,
                              void* d_out, int out_size, void* d_ws, size_t ws_size,
                              hipStream_t stream) {
    const int* cids = (const int*)d_in[0];
    const int* aids = (const int*)d_in[2];
    const float* amask = (const float*)d_in[3];
    const float* wordmat = (const float*)d_in[4];
    const float* Wm = (const float*)d_in[5];
    const float* ctx_w = (const float*)d_in[6];
    const float* ctx_b = (const float*)d_in[7];
    const float* gate_w = (const float*)d_in[8];
    const float* gate_b = (const float*)d_in[9];
    const float* lin_w = (const float*)d_in[10];
    const float* lin_b = (const float*)d_in[11];
    float* out = (float*)d_out;

    float* asp = (float*)d_ws;                                  // 1,228,800 f
    float* sbuf = asp + 1228800;                                // 2,097,152 f
    float* part = sbuf + 2097152;                               // 262,144 f
    __hip_bfloat16* albf = (__hip_bfloat16*)asp;                // alias: asp dead after prep_aspf
    __hip_bfloat16* aspb = (__hip_bfloat16*)(part + 262144);    // 1,310,720 bf16
    __hip_bfloat16* sybf = aspb + 1310720;                      // 1,310,720
    __hip_bfloat16* aspf = sybf + 1310720;                      // 1,245,184
    __hip_bfloat16* Wb = aspf + 1245184;                        // 97,280
    __hip_bfloat16* Wp2 = Wb + WB_ELEMS;                        // 933,888
    __hip_bfloat16* Xc = Wp2 + WP2_ELEMS;                       // 40,001,536

    prep_wp<<<(WP2_ELEMS + 255) / 256, 256, 0, stream>>>(ctx_w, gate_w, Wp2);
    prep_wb<<<(WB_ELEMS + 255) / 256, 256, 0, stream>>>(Wm, Wb);
    gather_rows<<<BB * L2, 256, 0, stream>>>(aids, wordmat, asp, aspb, sybf);
    prep_aspf<<<(BB * 19 * 512 + 255) / 256, 256, 0, stream>>>(asp, aspf);
    xcat_x<<<BB * L1 / 8, 256, 0, stream>>>(cids, wordmat, Xc);
    sy_mfma<<<(BB * L2) / 64, 256, 0, stream>>>(aspb, Wb, sybf);
    sxs_mfma<<<dim3(L1 / 64, BB), 256, 0, stream>>>(Xc, Wb, sybf, sbuf);
    softmax_col<<<dim3(BB, 2), 256, 0, stream>>>(sbuf, amask, albf);
    att_mfma<<<dim3(L1 / 64, BB), 256, 0, stream>>>(albf, aspf, Xc);
    conv_mfma<<<dim3(16, BB), 256, 0, stream>>>(Xc, Wp2, ctx_b, gate_b, part);
    finalize<<<BB, 256, 0, stream>>>(part, lin_w, lin_b, out);
}

// Round 7
// 195.470 us; speedup vs baseline: 17.2830x; 1.1055x over previous
//
#include <hip/hip_runtime.h>
#include <hip/hip_bf16.h>
#include <math.h>
#include <stdint.h>

#define DIM 300
#define NC 256
#define KS 3
#define NCLASS 3
#define BB 128
#define L1 512
#define L2 32

#define XW 352            // Xc row: [emb 0..299 | 0 300..319 | alpha 320..351]
#define XROWS 514         // guard row + 512 + guard row, per batch
#define ROW_B (XW * 2)    // 704 bytes = 11 x 64B chunks
#define NKC 11            // conv K-chunks (kc 0..9 static, kc 10 = alpha/G)
#define WP2_ELEMS (2 * 4 * 10 * 3 * 4 * 64 * 8)   // 491,520 static conv B-frags
#define WB_ELEMS (10 * 19 * 64 * 8)               // 97,280: W for sx/sy
#define WG2_ELEMS (3 * 10 * 16 * 64 * 8)          // 245,760: w2 B-frags for G
#define GT_ELEMS (BB * 3 * 32 * 256)              // 3,145,728 plain G
#define GP_ELEMS (BB * 2 * 2 * 3 * 4 * 64 * 8)    // 1,572,864 G conv-B-frags
#define GP_B_STRIDE (2 * 2 * 3 * 4 * 64 * 8)      // 12,288 elems per batch
#define WAVE_WP_B (10 * 3 * 4 * 1024)             // 122,880 B per (cb,role)

#define ABUF_B 4224       // one A double-buffer half (66 rows x 64B)
#define EP_LD 260         // padded epilogue stride (floats)

typedef __attribute__((ext_vector_type(8))) short bf16x8;
typedef __attribute__((ext_vector_type(4))) short bf16x4;
typedef __attribute__((ext_vector_type(4))) float f32x4;

#define GLOBAL_AS __attribute__((address_space(1)))
#define LDS_AS __attribute__((address_space(3)))

__device__ __forceinline__ void gload_lds16(const void* g, void* l) {
    __builtin_amdgcn_global_load_lds((const GLOBAL_AS void*)g, (LDS_AS void*)l, 16, 0, 0);
}

static __device__ __forceinline__ short bfr(float x) {
    __hip_bfloat16 h = __float2bfloat16(x);
    return *(short*)&h;
}

// ---------------- static conv weight pre-pack: Wp2[cb][role][kc<10][tap][n][lane][8]
// roles 0,1 = sentiment (ctx_w), roles 2,3 = gate emb-part (gate_w d<300)
__global__ void prep_wp(const float* __restrict__ ctx_w,
                        const float* __restrict__ gate_w,
                        __hip_bfloat16* __restrict__ Wp2) {
    int idx = blockIdx.x * 256 + threadIdx.x;
    if (idx >= WP2_ELEMS) return;
    int jj = idx & 7;
    int lane = (idx >> 3) & 63;
    int n = (idx >> 9) & 3;
    int rest = idx >> 11;
    int tap = rest % 3;
    int r2 = rest / 3;
    int kc = r2 % 10;
    int w = r2 / 10;
    int role = w & 3, cbv = w >> 2;
    int k = kc * 32 + ((lane >> 4) << 3) + jj;       // 0..319
    int nl = role * 64 + n * 16 + (lane & 15);       // 0..255
    float v = 0.f;
    if (nl < 128) {
        int ch = cbv * 128 + nl;
        if (k < 300) v = ctx_w[(ch * DIM + k) * KS + tap];
    } else {
        int ch = cbv * 128 + (nl - 128);
        if (k < 300) v = gate_w[(ch * 2 * DIM + k) * KS + tap];
    }
    Wp2[idx] = __float2bfloat16(v);
}

// ---------------- W pre-pack for sx/sy GEMMs (zero-padded)
__global__ void prep_wb(const float* __restrict__ Wm,
                        __hip_bfloat16* __restrict__ Wb) {
    int idx = blockIdx.x * 256 + threadIdx.x;
    if (idx >= WB_ELEMS) return;
    int j = idx & 7;
    int l = (idx >> 3) & 63;
    int r = idx >> 9;
    int nf = r % 19, kc = r / 19;
    int k = kc * 32 + ((l >> 4) << 3) + j;
    int n = nf * 16 + (l & 15);
    float v = (k < 300 && n < 300) ? Wm[k * DIM + n] : 0.f;
    Wb[idx] = __float2bfloat16(v);
}

// ---------------- w2 (gate att-part) B-frag pack: Wg2[tap][kc][nf][lane][8]
__global__ void prep_wg2(const float* __restrict__ gate_w,
                         __hip_bfloat16* __restrict__ Wg2) {
    int idx = blockIdx.x * 256 + threadIdx.x;
    if (idx >= WG2_ELEMS) return;
    int jj = idx & 7;
    int lane = (idx >> 3) & 63;
    int rest = idx >> 9;
    int nf = rest % 16;
    int r2 = rest / 16;
    int kc = r2 % 10, tap = r2 / 10;
    int k = kc * 32 + ((lane >> 4) << 3) + jj;       // d index 0..319
    int n = nf * 16 + (lane & 15);                   // channel 0..255
    float v = (k < 300) ? gate_w[(n * 2 * DIM + DIM + k) * KS + tap] : 0.f;
    Wg2[idx] = __float2bfloat16(v);
}

// ---------------- aspect gather: bf16 padded (+ sy pad zeros)
__global__ void gather_rows(const int* __restrict__ ids,
                            const float* __restrict__ wordmat,
                            __hip_bfloat16* __restrict__ aspb,
                            __hip_bfloat16* __restrict__ syb) {
    int row = blockIdx.x;
    int id = ids[row];
    const float* src = wordmat + (size_t)id * DIM;
    for (int d = threadIdx.x; d < 320; d += blockDim.x) {
        if (d < DIM) {
            aspb[(size_t)row * 320 + d] = __float2bfloat16(src[d]);
        } else {
            aspb[(size_t)row * 320 + d] = __float2bfloat16(0.f);
            if (d >= 304) syb[(size_t)row * 320 + d] = __float2bfloat16(0.f);
        }
    }
}

// ---------------- G[b,tap] = aspect[b] @ w2[:,:,tap]^T  (M=32, N=256, K=300)
__global__ __launch_bounds__(256, 2) void prep_g(
        const __hip_bfloat16* __restrict__ aspb,
        const __hip_bfloat16* __restrict__ Wg2,
        __hip_bfloat16* __restrict__ Gt) {
    const int t = threadIdx.x, wave = t >> 6, l = t & 63;
    const int lane15 = l & 15, lq = l >> 4;
    const int b = blockIdx.x, tap = blockIdx.y;
    f32x4 acc[2][4];
    #pragma unroll
    for (int m = 0; m < 2; ++m)
        #pragma unroll
        for (int ni = 0; ni < 4; ++ni) acc[m][ni] = (f32x4)0.f;
    const char* Ab = (const char*)aspb + (size_t)b * 32 * 640;
    const bf16x8* WgV = (const bf16x8*)Wg2;
    for (int kc = 0; kc < 10; ++kc) {
        bf16x8 af[2];
        #pragma unroll
        for (int m = 0; m < 2; ++m)
            af[m] = *(const bf16x8*)(Ab + (size_t)(m * 16 + lane15) * 640 + kc * 64 + lq * 16);
        #pragma unroll
        for (int ni = 0; ni < 4; ++ni) {
            bf16x8 bw = WgV[((size_t)(tap * 10 + kc) * 16 + wave * 4 + ni) * 64 + l];
            #pragma unroll
            for (int m = 0; m < 2; ++m)
                acc[m][ni] = __builtin_amdgcn_mfma_f32_16x16x32_bf16(af[m], bw, acc[m][ni], 0, 0, 0);
        }
    }
    #pragma unroll
    for (int m = 0; m < 2; ++m)
        #pragma unroll
        for (int ni = 0; ni < 4; ++ni) {
            int c = (wave * 4 + ni) * 16 + lane15;
            #pragma unroll
            for (int i2 = 0; i2 < 4; ++i2) {
                int j = m * 16 + lq * 4 + i2;
                Gt[((size_t)(b * 3 + tap) * 32 + j) * 256 + c] = __float2bfloat16(acc[m][ni][i2]);
            }
        }
}

// ---------------- repack G into conv B-frag layout Gp[b][cb][gr][tap][nf][lane][8]
__global__ void prep_gp(const __hip_bfloat16* __restrict__ Gt,
                        __hip_bfloat16* __restrict__ Gp) {
    int idx = blockIdx.x * 256 + threadIdx.x;
    if (idx >= GP_ELEMS) return;
    int jj = idx & 7;
    int lane = (idx >> 3) & 63;
    int nf = (idx >> 9) & 3;
    int rest = idx >> 11;
    int tap = rest % 3;
    int r2 = rest / 3;
    int gr = r2 & 1, cbv = (r2 >> 1) & 1, b = r2 >> 2;
    int j = ((lane >> 4) << 3) + jj;                       // 0..31
    int c = cbv * 128 + gr * 64 + nf * 16 + (lane & 15);   // 0..255
    Gp[idx] = Gt[((size_t)(b * 3 + tap) * 32 + j) * 256 + c];
}

// ---------------- Xcat x-part: vectorized bf16 gather + pad + guard rows
__global__ __launch_bounds__(256) void xcat_x(const int* __restrict__ cids,
                                              const float* __restrict__ wordmat,
                                              __hip_bfloat16* __restrict__ Xc) {
    int t = threadIdx.x;
    int rloc = t >> 5, lane = t & 31;
    int row = blockIdx.x * 8 + rloc;          // 0..65535
    int b = row >> 9, l = row & 511;
    size_t id = (size_t)cids[row];
    const float4* src = (const float4*)(wordmat + id * DIM);
    __hip_bfloat16* dst = Xc + ((size_t)b * XROWS + 1 + l) * XW;
    #pragma unroll
    for (int c = lane; c < 80; c += 32) {     // cols 0..319 (alpha written later)
        bf16x4 o;
        if (c < 75) {
            float4 f = src[c];
            o[0] = bfr(f.x); o[1] = bfr(f.y); o[2] = bfr(f.z); o[3] = bfr(f.w);
        } else {
            o = (bf16x4)0;   // cols 300..319
        }
        ((bf16x4*)dst)[c] = o;
    }
    // zero guard rows (256 of them), 704B each via 8B stores
    if (blockIdx.x < 256 && t < 88) {
        int b2 = blockIdx.x >> 1;
        int gr = (blockIdx.x & 1) ? (XROWS - 1) : 0;
        ((bf16x4*)(Xc + ((size_t)b2 * XROWS + gr) * XW))[t] = (bf16x4)0;
    }
}

// ---------------- sy = relu(aspect @ W) via MFMA, direct-from-global
__global__ __launch_bounds__(256, 2) void sy_mfma(
        const __hip_bfloat16* __restrict__ aspb,
        const __hip_bfloat16* __restrict__ Wb,
        __hip_bfloat16* __restrict__ syb) {
    const int t = threadIdx.x, wave = t >> 6, l = t & 63;
    const int lane15 = l & 15, lq = l >> 4;
    const int g = blockIdx.x * 64 + wave * 16 + lane15;
    f32x4 acc[19];
    #pragma unroll
    for (int nf = 0; nf < 19; ++nf) acc[nf] = (f32x4)0.f;
    const bf16x8* Arow = (const bf16x8*)((const char*)aspb + (size_t)g * 640);
    const bf16x8* WbV = (const bf16x8*)Wb;
    for (int kc = 0; kc < 10; ++kc) {
        bf16x8 af = Arow[kc * 4 + lq];
        #pragma unroll
        for (int nf = 0; nf < 19; ++nf)
            acc[nf] = __builtin_amdgcn_mfma_f32_16x16x32_bf16(
                af, WbV[(kc * 19 + nf) * 64 + l], acc[nf], 0, 0, 0);
    }
    #pragma unroll
    for (int nf = 0; nf < 19; ++nf) {
        int col = nf * 16 + lane15;
        #pragma unroll
        for (int i2 = 0; i2 < 4; ++i2) {
            int row = blockIdx.x * 64 + wave * 16 + lq * 4 + i2;
            syb[(size_t)row * 320 + col] = __float2bfloat16(fmaxf(acc[nf][i2], 0.f));
        }
    }
}

// ---------------- fused sx+s (guard-row layout), no syncthreads
__global__ __launch_bounds__(256, 2) void sxs_mfma(
        const __hip_bfloat16* __restrict__ Xc,
        const __hip_bfloat16* __restrict__ Wb,
        const __hip_bfloat16* __restrict__ syb,
        float* __restrict__ s) {
    __shared__ __align__(16) char sxL[4 * 16 * 640];  // 40KB, wave-private
    const int t = threadIdx.x, wave = t >> 6, l = t & 63;
    const int lane15 = l & 15, lq = l >> 4;
    const int lb = blockIdx.x, b = blockIdx.y;
    const int g = b * XROWS + 1 + lb * 64 + wave * 16 + lane15;

    f32x4 acc[19];
    #pragma unroll
    for (int nf = 0; nf < 19; ++nf) acc[nf] = (f32x4)0.f;

    const bf16x8* Arow = (const bf16x8*)((const char*)Xc + (size_t)g * ROW_B);
    const bf16x8* WbV = (const bf16x8*)Wb;
    for (int kc = 0; kc < 10; ++kc) {
        bf16x8 af = Arow[kc * 4 + lq];
        #pragma unroll
        for (int nf = 0; nf < 19; ++nf)
            acc[nf] = __builtin_amdgcn_mfma_f32_16x16x32_bf16(
                af, WbV[(kc * 19 + nf) * 64 + l], acc[nf], 0, 0, 0);
    }

    char* sxW = sxL + wave * (16 * 640);
    if (l < 32) {
        int row = l >> 1;
        int phys = (2 + (l & 1)) ^ ((row >> 2) & 3);
        *(f32x4*)(sxW + row * 640 + 576 + phys * 16) = (f32x4)0.f;
    }
    #pragma unroll
    for (int nf = 0; nf < 19; ++nf) {
        int col = nf * 16 + lane15;
        #pragma unroll
        for (int i2 = 0; i2 < 4; ++i2) {
            int row = lq * 4 + i2;
            int off = row * 640 + ((col >> 5) << 6) +
                      ((((col >> 3) & 3) ^ ((row >> 2) & 3)) << 4) + ((col & 7) << 1);
            *(__hip_bfloat16*)(sxW + off) = __float2bfloat16(fmaxf(acc[nf][i2], 0.f));
        }
    }
    f32x4 acc2[2];
    acc2[0] = (f32x4)0.f;
    acc2[1] = (f32x4)0.f;
    const bf16x8* syV = (const bf16x8*)syb + (size_t)b * 32 * 40;
    for (int kc = 0; kc < 10; ++kc) {
        bf16x8 af2 = *(const bf16x8*)(sxW + lane15 * 640 + kc * 64 +
                                      ((lq ^ ((lane15 >> 2) & 3)) << 4));
        #pragma unroll
        for (int nj = 0; nj < 2; ++nj) {
            bf16x8 bfj = syV[(nj * 16 + lane15) * 40 + kc * 4 + lq];
            acc2[nj] = __builtin_amdgcn_mfma_f32_16x16x32_bf16(af2, bfj, acc2[nj], 0, 0, 0);
        }
    }
    #pragma unroll
    for (int nj = 0; nj < 2; ++nj)
        #pragma unroll
        for (int i2 = 0; i2 < 4; ++i2) {
            int i = lb * 64 + wave * 16 + lq * 4 + i2;
            s[((size_t)b * L1 + i) * L2 + nj * 16 + lane15] = acc2[nj][i2];
        }
}

// ---------------- softmax over dim=1 (L1): bf16 alpha straight into Xc[320..351]
__global__ __launch_bounds__(256) void softmax_col(const float* __restrict__ s,
                                                   const float* __restrict__ amask,
                                                   __hip_bfloat16* __restrict__ Xc) {
    __shared__ float red[256];
    __shared__ float cmax[16], cscale[16];
    int b = blockIdx.x, jh = blockIdx.y, t = threadIdx.x;
    int jl = t & 15, j = jh * 16 + jl, ii = t >> 4;
    const float* sb = s + (size_t)b * L1 * L2;
    float v[32];
    float m = -1e30f;
    #pragma unroll
    for (int q = 0; q < 32; ++q) {
        v[q] = sb[(size_t)(ii + q * 16) * L2 + j];
        m = fmaxf(m, v[q]);
    }
    red[t] = m;
    __syncthreads();
    if (t < 16) {
        float mm = red[t];
        for (int p = 1; p < 16; ++p) mm = fmaxf(mm, red[p * 16 + t]);
        cmax[t] = mm;
    }
    __syncthreads();
    float cm = cmax[jl];
    float sum = 0.f;
    #pragma unroll
    for (int q = 0; q < 32; ++q) {
        v[q] = expf(v[q] - cm);
        sum += v[q];
    }
    red[t] = sum;
    __syncthreads();
    if (t < 16) {
        float ss = 0.f;
        for (int p = 0; p < 16; ++p) ss += red[p * 16 + t];
        float mk = amask[b * L2 + jh * 16 + t];
        cscale[t] = mk / (mk * ss + 1e-10f);
    }
    __syncthreads();
    float sc = cscale[jl];
    #pragma unroll
    for (int q = 0; q < 32; ++q) {
        int row = ii + q * 16;
        Xc[((size_t)b * XROWS + 1 + row) * XW + 320 + j] = __float2bfloat16(v[q] * sc);
    }
}

// ---------------- conv GEMM v5: 64-row blocks, A dbuf in LDS, B direct-global.
// kc 0..9 static weights; kc 10 = alpha x per-batch G fragments (gate only).
__global__ __launch_bounds__(256, 4) void conv_mfma(
        const __hip_bfloat16* __restrict__ Xc,
        const __hip_bfloat16* __restrict__ Wp2,
        const __hip_bfloat16* __restrict__ Gp,
        const float* __restrict__ ctx_b,
        const float* __restrict__ gate_b,
        float* __restrict__ part) {
    __shared__ __align__(16) char lds[16 * EP_LD * 4];   // 16.6KB; stage aliases front
    const int t = threadIdx.x, wave = t >> 6, lane = t & 63;
    const int lane15 = lane & 15, lq = lane >> 4;
    const int lb = blockIdx.x >> 1, cb = blockIdx.x & 1;
    const int b = blockIdx.y, l0 = lb * 64;
    const int role = wave ^ ((blockIdx.x & 1) << 1);

    f32x4 acc[4][4];
    #pragma unroll
    for (int m = 0; m < 4; ++m)
        #pragma unroll
        for (int n = 0; n < 4; ++n) acc[m][n] = (f32x4)0.f;

    const char* XcB = (const char*)Xc + ((size_t)b * XROWS + l0) * ROW_B;
    const char* bbase = (const char*)Wp2 + (size_t)(cb * 4 + role) * WAVE_WP_B + lane * 16;
    // per-batch G fragments for this wave (gate roles): [cb][gr][tap][nf][lane][8]
    const char* gbase = (const char*)Gp + ((size_t)b * GP_B_STRIDE +
                        (size_t)(cb * 2 + (role & 1)) * (3 * 4 * 512)) * 2 + lane * 16;

    #define STAGE_A(kc_, buf_) do {                                              \
        char* Ab_ = lds + (buf_) * ABUF_B;                                       \
        _Pragma("unroll")                                                        \
        for (int i = 0; i < 2; ++i) {                                            \
            int chunk = (i * 4 + wave) * 64 + lane;                              \
            if (chunk < 264) {                                                   \
                int row_ = chunk >> 2, c_ = chunk & 3;                           \
                int sc_ = (c_ ^ ((row_ >> 1) & 3)) << 4;                         \
                gload_lds16(XcB + (size_t)row_ * ROW_B + (kc_) * 64 + sc_,       \
                            Ab_ + (i * 4 + wave) * 1024);                        \
            }                                                                    \
        }                                                                        \
    } while (0)

    STAGE_A(0, 0);
    __syncthreads();

    for (int kc = 0; kc < NKC; ++kc) {
        const int cbuf = kc & 1;
        if (kc < NKC - 1) STAGE_A(kc + 1, cbuf ^ 1);
        if (kc < 10 || role >= 2) {
            const char* Ab = lds + cbuf * ABUF_B;
            #pragma unroll
            for (int tap = 0; tap < 3; ++tap) {
                bf16x8 bw[4];
                #pragma unroll
                for (int n = 0; n < 4; ++n)
                    bw[n] = (kc < 10)
                        ? *(const bf16x8*)(bbase + (size_t)((kc * 3 + tap) * 4 + n) * 1024)
                        : *(const bf16x8*)(gbase + (size_t)(tap * 4 + n) * 1024);
                bf16x8 af[4];
                #pragma unroll
                for (int m = 0; m < 4; ++m) {
                    int row = m * 16 + lane15 + tap;
                    af[m] = *(const bf16x8*)(Ab + row * 64 +
                                             ((lq ^ ((row >> 1) & 3)) << 4));
                }
                #pragma unroll
                for (int m = 0; m < 4; ++m)
                    #pragma unroll
                    for (int n = 0; n < 4; ++n)
                        acc[m][n] = __builtin_amdgcn_mfma_f32_16x16x32_bf16(
                            af[m], bw[n], acc[m][n], 0, 0, 0);
            }
        }
        __syncthreads();
    }
    #undef STAGE_A

    // epilogue: cross-wave combine sent x gate, maxpool (padded stride EP_LD)
    const int c0 = cb * 128;
    const int cl = t & 127, rh = t >> 7;
    const float bs = ctx_b[c0 + cl];
    const float bg = gate_b[c0 + cl];
    float* ep = (float*)lds;
    float pm = -1e30f;
    for (int ms = 0; ms < 4; ++ms) {
        __syncthreads();
        #pragma unroll
        for (int n = 0; n < 4; ++n) {
            int col = (role << 6) + (n << 4) + lane15;
            #pragma unroll
            for (int i2 = 0; i2 < 4; ++i2)
                ep[(lq * 4 + i2) * EP_LD + col] = acc[ms][n][i2];
        }
        __syncthreads();
        #pragma unroll
        for (int rr = 0; rr < 8; ++rr) {
            int r = rh * 8 + rr;
            float sv = ep[r * EP_LD + cl] + bs;
            float gv = ep[r * EP_LD + 128 + cl] + bg;
            pm = fmaxf(pm, tanhf(sv) * fmaxf(gv, 0.f));
        }
    }
    __syncthreads();
    ep[t] = pm;
    __syncthreads();
    if (t < 128)
        part[((size_t)b * 8 + lb) * 256 + c0 + cl] = fmaxf(ep[t], ep[t + 128]);
}

// ---------------- final: max over 8 l-blocks + linear
__global__ __launch_bounds__(256) void finalize(const float* __restrict__ part,
                                                const float* __restrict__ lin_w,
                                                const float* __restrict__ lin_b,
                                                float* __restrict__ out) {
    __shared__ float pl[256];
    __shared__ float red[256];
    int b = blockIdx.x, t = threadIdx.x;
    float p = part[((size_t)b * 8) * 256 + t];
    for (int lb = 1; lb < 8; ++lb)
        p = fmaxf(p, part[((size_t)b * 8 + lb) * 256 + t]);
    pl[t] = p;
    __syncthreads();
    for (int n = 0; n < NCLASS; ++n) {
        red[t] = pl[t] * lin_w[n * NC + t];
        __syncthreads();
        for (int sft = 128; sft > 0; sft >>= 1) {
            if (t < sft) red[t] += red[t + sft];
            __syncthreads();
        }
        if (t == 0) out[b * NCLASS + n] = red[0] + lin_b[n];
        __syncthreads();
    }
}

extern "C" void kernel_launch(void* const* d_in, const int* in_sizes, int n_in,
                              void* d_out, int out_size, void* d_ws, size_t ws_size,
                              hipStream_t stream) {
    const int* cids = (const int*)d_in[0];
    const int* aids = (const int*)d_in[2];
    const float* amask = (const float*)d_in[3];
    const float* wordmat = (const float*)d_in[4];
    const float* Wm = (const float*)d_in[5];
    const float* ctx_w = (const float*)d_in[6];
    const float* ctx_b = (const float*)d_in[7];
    const float* gate_w = (const float*)d_in[8];
    const float* gate_b = (const float*)d_in[9];
    const float* lin_w = (const float*)d_in[10];
    const float* lin_b = (const float*)d_in[11];
    float* out = (float*)d_out;

    float* sbuf = (float*)d_ws;                                 // 2,097,152 f
    float* part = sbuf + 2097152;                               // 262,144 f
    __hip_bfloat16* aspb = (__hip_bfloat16*)(part + 262144);    // 1,310,720 bf16
    __hip_bfloat16* sybf = aspb + 1310720;                      // 1,310,720
    __hip_bfloat16* Wb   = sybf + 1310720;                      // 97,280
    __hip_bfloat16* Wp2  = Wb + WB_ELEMS;                       // 491,520
    __hip_bfloat16* Wg2  = Wp2 + WP2_ELEMS;                     // 245,760
    __hip_bfloat16* Gt   = Wg2 + WG2_ELEMS;                     // 3,145,728
    __hip_bfloat16* Gp   = Gt + GT_ELEMS;                       // 1,572,864
    __hip_bfloat16* Xc   = Gp + GP_ELEMS;                       // 23,158,784

    prep_wp<<<(WP2_ELEMS + 255) / 256, 256, 0, stream>>>(ctx_w, gate_w, Wp2);
    prep_wb<<<(WB_ELEMS + 255) / 256, 256, 0, stream>>>(Wm, Wb);
    prep_wg2<<<(WG2_ELEMS + 255) / 256, 256, 0, stream>>>(gate_w, Wg2);
    gather_rows<<<BB * L2, 256, 0, stream>>>(aids, wordmat, aspb, sybf);
    xcat_x<<<BB * L1 / 8, 256, 0, stream>>>(cids, wordmat, Xc);
    sy_mfma<<<(BB * L2) / 64, 256, 0, stream>>>(aspb, Wb, sybf);
    prep_g<<<dim3(BB, 3), 256, 0, stream>>>(aspb, Wg2, Gt);
    prep_gp<<<(GP_ELEMS + 255) / 256, 256, 0, stream>>>(Gt, Gp);
    sxs_mfma<<<dim3(L1 / 64, BB), 256, 0, stream>>>(Xc, Wb, sybf, sbuf);
    softmax_col<<<dim3(BB, 2), 256, 0, stream>>>(sbuf, amask, Xc);
    conv_mfma<<<dim3(16, BB), 256, 0, stream>>>(Xc, Wp2, Gp, ctx_b, gate_b, part);
    finalize<<<BB, 256, 0, stream>>>(part, lin_w, lin_b, out);
}

// Round 8
// 171.647 us; speedup vs baseline: 19.6818x; 1.1388x over previous
//
#include <hip/hip_runtime.h>
#include <hip/hip_bf16.h>
#include <math.h>
#include <stdint.h>

#define DIM 300
#define NC 256
#define KS 3
#define NCLASS 3
#define BB 128
#define L1 512
#define L2 32

#define XW 352            // Xc row: [emb 0..299 | 0 300..319 | alpha 320..351]
#define XROWS 514         // guard row + 512 + guard row, per batch
#define ROW_B (XW * 2)    // 704 bytes = 11 x 64B chunks
#define NKC 11            // conv K-chunks (kc 0..9 static, kc 10 = alpha x G)
#define WP2_ELEMS (2 * 4 * 10 * 3 * 4 * 64 * 8)   // 491,520 static conv B-frags
#define WB_ELEMS (10 * 19 * 64 * 8)               // 97,280: W for sx/sy
#define WG2_ELEMS (3 * 10 * 16 * 64 * 8)          // 245,760: w2 B-frags for G
#define GT_ELEMS (BB * 3 * 32 * 256)              // 3,145,728 plain G
#define GATH_ELEMS (BB * L2 * 320)                // 1,310,720 aspect gather
#define WAVE_WP_B (10 * 3 * 4 * 1024)             // 122,880 B per (cb,role)

#define ABUF_B 4224       // one A double-buffer half (66 rows x 64B)
#define EP_LD 516         // epilogue stride (floats), 512 cols + pad

typedef __attribute__((ext_vector_type(8))) short bf16x8;
typedef __attribute__((ext_vector_type(4))) short bf16x4;
typedef __attribute__((ext_vector_type(4))) float f32x4;

#define GLOBAL_AS __attribute__((address_space(1)))
#define LDS_AS __attribute__((address_space(3)))

__device__ __forceinline__ void gload_lds16(const void* g, void* l) {
    __builtin_amdgcn_global_load_lds((const GLOBAL_AS void*)g, (LDS_AS void*)l, 16, 0, 0);
}

static __device__ __forceinline__ short bfr(float x) {
    __hip_bfloat16 h = __float2bfloat16(x);
    return *(short*)&h;
}

// ---------------- one flat prep kernel: conv B-frags | W B-frags | w2 B-frags | aspect gather
__global__ void prep_all(const float* __restrict__ ctx_w,
                         const float* __restrict__ gate_w,
                         const float* __restrict__ Wm,
                         const int* __restrict__ aids,
                         const float* __restrict__ wordmat,
                         __hip_bfloat16* __restrict__ Wp2,
                         __hip_bfloat16* __restrict__ Wb,
                         __hip_bfloat16* __restrict__ Wg2,
                         __hip_bfloat16* __restrict__ aspb,
                         __hip_bfloat16* __restrict__ syb) {
    int idx = blockIdx.x * 256 + threadIdx.x;
    if (idx < WP2_ELEMS) {
        int jj = idx & 7;
        int lane = (idx >> 3) & 63;
        int n = (idx >> 9) & 3;
        int rest = idx >> 11;
        int tap = rest % 3;
        int r2 = rest / 3;
        int kc = r2 % 10;
        int w = r2 / 10;
        int role = w & 3, cbv = w >> 2;
        int k = kc * 32 + ((lane >> 4) << 3) + jj;
        int nl = role * 64 + n * 16 + (lane & 15);
        float v = 0.f;
        if (nl < 128) {
            int ch = cbv * 128 + nl;
            if (k < 300) v = ctx_w[(ch * DIM + k) * KS + tap];
        } else {
            int ch = cbv * 128 + (nl - 128);
            if (k < 300) v = gate_w[(ch * 2 * DIM + k) * KS + tap];
        }
        Wp2[idx] = __float2bfloat16(v);
        return;
    }
    idx -= WP2_ELEMS;
    if (idx < WB_ELEMS) {
        int j = idx & 7;
        int l = (idx >> 3) & 63;
        int r = idx >> 9;
        int nf = r % 19, kc = r / 19;
        int k = kc * 32 + ((l >> 4) << 3) + j;
        int n = nf * 16 + (l & 15);
        float v = (k < 300 && n < 300) ? Wm[k * DIM + n] : 0.f;
        Wb[idx] = __float2bfloat16(v);
        return;
    }
    idx -= WB_ELEMS;
    if (idx < WG2_ELEMS) {
        int jj = idx & 7;
        int lane = (idx >> 3) & 63;
        int rest = idx >> 9;
        int nf = rest % 16;
        int r2 = rest / 16;
        int kc = r2 % 10, tap = r2 / 10;
        int k = kc * 32 + ((lane >> 4) << 3) + jj;
        int n = nf * 16 + (lane & 15);
        float v = (k < 300) ? gate_w[(n * 2 * DIM + DIM + k) * KS + tap] : 0.f;
        Wg2[idx] = __float2bfloat16(v);
        return;
    }
    idx -= WG2_ELEMS;
    if (idx < GATH_ELEMS) {
        int row = idx / 320, d = idx - row * 320;
        if (d < DIM) {
            aspb[(size_t)row * 320 + d] = __float2bfloat16(wordmat[(size_t)aids[row] * DIM + d]);
        } else {
            aspb[(size_t)row * 320 + d] = __float2bfloat16(0.f);
            if (d >= 304) syb[(size_t)row * 320 + d] = __float2bfloat16(0.f);
        }
    }
}

// ---------------- Xcat x-part: vectorized bf16 gather + pad + guard rows
__global__ __launch_bounds__(256) void xcat_x(const int* __restrict__ cids,
                                              const float* __restrict__ wordmat,
                                              __hip_bfloat16* __restrict__ Xc) {
    int t = threadIdx.x;
    int rloc = t >> 5, lane = t & 31;
    int row = blockIdx.x * 8 + rloc;          // 0..65535
    int b = row >> 9, l = row & 511;
    size_t id = (size_t)cids[row];
    const float4* src = (const float4*)(wordmat + id * DIM);
    __hip_bfloat16* dst = Xc + ((size_t)b * XROWS + 1 + l) * XW;
    #pragma unroll
    for (int c = lane; c < 80; c += 32) {     // cols 0..319 (alpha written later)
        bf16x4 o;
        if (c < 75) {
            float4 f = src[c];
            o[0] = bfr(f.x); o[1] = bfr(f.y); o[2] = bfr(f.z); o[3] = bfr(f.w);
        } else {
            o = (bf16x4)0;   // cols 300..319
        }
        ((bf16x4*)dst)[c] = o;
    }
    // zero guard rows (256 of them), 704B each via 8B stores
    if (blockIdx.x < 256 && t < 88) {
        int b2 = blockIdx.x >> 1;
        int gr = (blockIdx.x & 1) ? (XROWS - 1) : 0;
        ((bf16x4*)(Xc + ((size_t)b2 * XROWS + gr) * XW))[t] = (bf16x4)0;
    }
}

// ---------------- merged aspect MFMA: sy = relu(aspect@W) [blocks 0..63]
//                  and G[b,tap] = aspect[b] @ w2^T [blocks 64..447]
__global__ __launch_bounds__(256, 2) void asp_mfma(
        const __hip_bfloat16* __restrict__ aspb,
        const __hip_bfloat16* __restrict__ Wb,
        const __hip_bfloat16* __restrict__ Wg2,
        __hip_bfloat16* __restrict__ syb,
        __hip_bfloat16* __restrict__ Gt) {
    const int t = threadIdx.x, wave = t >> 6, l = t & 63;
    const int lane15 = l & 15, lq = l >> 4;
    if (blockIdx.x < 64) {
        const int g = blockIdx.x * 64 + wave * 16 + lane15;
        f32x4 acc[19];
        #pragma unroll
        for (int nf = 0; nf < 19; ++nf) acc[nf] = (f32x4)0.f;
        const bf16x8* Arow = (const bf16x8*)((const char*)aspb + (size_t)g * 640);
        const bf16x8* WbV = (const bf16x8*)Wb;
        for (int kc = 0; kc < 10; ++kc) {
            bf16x8 af = Arow[kc * 4 + lq];
            #pragma unroll
            for (int nf = 0; nf < 19; ++nf)
                acc[nf] = __builtin_amdgcn_mfma_f32_16x16x32_bf16(
                    af, WbV[(kc * 19 + nf) * 64 + l], acc[nf], 0, 0, 0);
        }
        #pragma unroll
        for (int nf = 0; nf < 19; ++nf) {
            int col = nf * 16 + lane15;
            #pragma unroll
            for (int i2 = 0; i2 < 4; ++i2) {
                int row = blockIdx.x * 64 + wave * 16 + lq * 4 + i2;
                syb[(size_t)row * 320 + col] = __float2bfloat16(fmaxf(acc[nf][i2], 0.f));
            }
        }
    } else {
        const int i = blockIdx.x - 64;
        const int b = i / 3, tap = i - b * 3;
        f32x4 acc[2][4];
        #pragma unroll
        for (int m = 0; m < 2; ++m)
            #pragma unroll
            for (int ni = 0; ni < 4; ++ni) acc[m][ni] = (f32x4)0.f;
        const char* Ab = (const char*)aspb + (size_t)b * 32 * 640;
        const bf16x8* WgV = (const bf16x8*)Wg2;
        for (int kc = 0; kc < 10; ++kc) {
            bf16x8 af[2];
            #pragma unroll
            for (int m = 0; m < 2; ++m)
                af[m] = *(const bf16x8*)(Ab + (size_t)(m * 16 + lane15) * 640 + kc * 64 + lq * 16);
            #pragma unroll
            for (int ni = 0; ni < 4; ++ni) {
                bf16x8 bw = WgV[((size_t)(tap * 10 + kc) * 16 + wave * 4 + ni) * 64 + l];
                #pragma unroll
                for (int m = 0; m < 2; ++m)
                    acc[m][ni] = __builtin_amdgcn_mfma_f32_16x16x32_bf16(af[m], bw, acc[m][ni], 0, 0, 0);
            }
        }
        #pragma unroll
        for (int m = 0; m < 2; ++m)
            #pragma unroll
            for (int ni = 0; ni < 4; ++ni) {
                int c = (wave * 4 + ni) * 16 + lane15;
                #pragma unroll
                for (int i2 = 0; i2 < 4; ++i2) {
                    int j = m * 16 + lq * 4 + i2;
                    Gt[((size_t)(b * 3 + tap) * 32 + j) * 256 + c] = __float2bfloat16(acc[m][ni][i2]);
                }
            }
    }
}

// ---------------- fused sx+s (guard-row layout), no syncthreads
__global__ __launch_bounds__(256, 2) void sxs_mfma(
        const __hip_bfloat16* __restrict__ Xc,
        const __hip_bfloat16* __restrict__ Wb,
        const __hip_bfloat16* __restrict__ syb,
        float* __restrict__ s) {
    __shared__ __align__(16) char sxL[4 * 16 * 640];  // 40KB, wave-private
    const int t = threadIdx.x, wave = t >> 6, l = t & 63;
    const int lane15 = l & 15, lq = l >> 4;
    const int lb = blockIdx.x, b = blockIdx.y;
    const int g = b * XROWS + 1 + lb * 64 + wave * 16 + lane15;

    f32x4 acc[19];
    #pragma unroll
    for (int nf = 0; nf < 19; ++nf) acc[nf] = (f32x4)0.f;

    const bf16x8* Arow = (const bf16x8*)((const char*)Xc + (size_t)g * ROW_B);
    const bf16x8* WbV = (const bf16x8*)Wb;
    for (int kc = 0; kc < 10; ++kc) {
        bf16x8 af = Arow[kc * 4 + lq];
        #pragma unroll
        for (int nf = 0; nf < 19; ++nf)
            acc[nf] = __builtin_amdgcn_mfma_f32_16x16x32_bf16(
                af, WbV[(kc * 19 + nf) * 64 + l], acc[nf], 0, 0, 0);
    }

    char* sxW = sxL + wave * (16 * 640);
    if (l < 32) {
        int row = l >> 1;
        int phys = (2 + (l & 1)) ^ ((row >> 2) & 3);
        *(f32x4*)(sxW + row * 640 + 576 + phys * 16) = (f32x4)0.f;
    }
    #pragma unroll
    for (int nf = 0; nf < 19; ++nf) {
        int col = nf * 16 + lane15;
        #pragma unroll
        for (int i2 = 0; i2 < 4; ++i2) {
            int row = lq * 4 + i2;
            int off = row * 640 + ((col >> 5) << 6) +
                      ((((col >> 3) & 3) ^ ((row >> 2) & 3)) << 4) + ((col & 7) << 1);
            *(__hip_bfloat16*)(sxW + off) = __float2bfloat16(fmaxf(acc[nf][i2], 0.f));
        }
    }
    f32x4 acc2[2];
    acc2[0] = (f32x4)0.f;
    acc2[1] = (f32x4)0.f;
    const bf16x8* syV = (const bf16x8*)syb + (size_t)b * 32 * 40;
    for (int kc = 0; kc < 10; ++kc) {
        bf16x8 af2 = *(const bf16x8*)(sxW + lane15 * 640 + kc * 64 +
                                      ((lq ^ ((lane15 >> 2) & 3)) << 4));
        #pragma unroll
        for (int nj = 0; nj < 2; ++nj) {
            bf16x8 bfj = syV[(nj * 16 + lane15) * 40 + kc * 4 + lq];
            acc2[nj] = __builtin_amdgcn_mfma_f32_16x16x32_bf16(af2, bfj, acc2[nj], 0, 0, 0);
        }
    }
    #pragma unroll
    for (int nj = 0; nj < 2; ++nj)
        #pragma unroll
        for (int i2 = 0; i2 < 4; ++i2) {
            int i = lb * 64 + wave * 16 + lq * 4 + i2;
            s[((size_t)b * L1 + i) * L2 + nj * 16 + lane15] = acc2[nj][i2];
        }
}

// ---------------- softmax over dim=1 (L1): bf16 alpha straight into Xc[320..351]
__global__ __launch_bounds__(256) void softmax_col(const float* __restrict__ s,
                                                   const float* __restrict__ amask,
                                                   __hip_bfloat16* __restrict__ Xc) {
    __shared__ float red[256];
    __shared__ float cmax[8], cscale[8];
    int b = blockIdx.x, jh = blockIdx.y, t = threadIdx.x;
    int jl = t & 7, j = jh * 8 + jl, ii = t >> 3;
    const float* sb = s + (size_t)b * L1 * L2;
    float v[16];
    float m = -1e30f;
    #pragma unroll
    for (int q = 0; q < 16; ++q) {
        v[q] = sb[(size_t)(ii + q * 32) * L2 + j];
        m = fmaxf(m, v[q]);
    }
    red[t] = m;
    __syncthreads();
    if (t < 8) {
        float mm = red[t];
        for (int p = 1; p < 32; ++p) mm = fmaxf(mm, red[p * 8 + t]);
        cmax[t] = mm;
    }
    __syncthreads();
    float cm = cmax[jl];
    float sum = 0.f;
    #pragma unroll
    for (int q = 0; q < 16; ++q) {
        v[q] = expf(v[q] - cm);
        sum += v[q];
    }
    red[t] = sum;
    __syncthreads();
    if (t < 8) {
        float ss = 0.f;
        for (int p = 0; p < 32; ++p) ss += red[p * 8 + t];
        float mk = amask[b * L2 + jh * 8 + t];
        cscale[t] = mk / (mk * ss + 1e-10f);
    }
    __syncthreads();
    float sc = cscale[jl];
    #pragma unroll
    for (int q = 0; q < 16; ++q) {
        int row = ii + q * 32;
        Xc[((size_t)b * XROWS + 1 + row) * XW + 320 + j] = __float2bfloat16(v[q] * sc);
    }
}

// ---------------- conv GEMM v6: 512-thr blocks (8 waves = 4 sent + 4 gate strips,
// all 256 channels), A staged ONCE per tile (half the fetch of v5), dbuf LDS,
// B direct-global; kc 10 = alpha x G with G-frags gathered from Gt (L2).
__global__ __launch_bounds__(512, 4) void conv_mfma(
        const __hip_bfloat16* __restrict__ Xc,
        const __hip_bfloat16* __restrict__ Wp2,
        const __hip_bfloat16* __restrict__ Gt,
        const float* __restrict__ ctx_b,
        const float* __restrict__ gate_b,
        float* __restrict__ part) {
    __shared__ __align__(16) char lds[16 * EP_LD * 4];   // 33,024 B; stage aliases front
    const int t = threadIdx.x, wave = t >> 6, lane = t & 63;
    const int lane15 = lane & 15, lq = lane >> 4;
    const int lb = blockIdx.x, b = blockIdx.y, l0 = lb * 64;
    const bool isGate = wave >= 4;
    const int u = isGate ? wave - 4 : wave;        // strip index 0..3
    const int cbv = u >> 1;
    const int role = isGate ? 2 + (u & 1) : (u & 1);

    f32x4 acc[4][4];
    #pragma unroll
    for (int m = 0; m < 4; ++m)
        #pragma unroll
        for (int n = 0; n < 4; ++n) acc[m][n] = (f32x4)0.f;

    const char* XcB = (const char*)Xc + ((size_t)b * XROWS + l0) * ROW_B;
    const char* bbase = (const char*)Wp2 + (size_t)(cbv * 4 + role) * WAVE_WP_B + lane * 16;

    // stage A-tile: 66 rows x 64B = 264 chunks over 8 waves (1 issue/wave)
    #define STAGE_A(kc_, buf_) do {                                              \
        char* Ab_ = lds + (buf_) * ABUF_B;                                       \
        int chunk = wave * 64 + lane;                                            \
        if (chunk < 264) {                                                       \
            int row_ = chunk >> 2, c_ = chunk & 3;                               \
            int sc_ = (c_ ^ ((row_ >> 1) & 3)) << 4;                             \
            gload_lds16(XcB + (size_t)row_ * ROW_B + (kc_) * 64 + sc_,           \
                        Ab_ + wave * 1024);                                      \
        }                                                                        \
    } while (0)

    STAGE_A(0, 0);
    __syncthreads();

    for (int kc = 0; kc < NKC; ++kc) {
        const int cbuf = kc & 1;
        if (kc < NKC - 1) STAGE_A(kc + 1, cbuf ^ 1);
        const char* Ab = lds + cbuf * ABUF_B;
        if (kc < 10) {
            #pragma unroll
            for (int tap = 0; tap < 3; ++tap) {
                bf16x8 bw[4];
                #pragma unroll
                for (int n = 0; n < 4; ++n)
                    bw[n] = *(const bf16x8*)(bbase + (size_t)((kc * 3 + tap) * 4 + n) * 1024);
                bf16x8 af[4];
                #pragma unroll
                for (int m = 0; m < 4; ++m) {
                    int row = m * 16 + lane15 + tap;
                    af[m] = *(const bf16x8*)(Ab + row * 64 + ((lq ^ ((row >> 1) & 3)) << 4));
                }
                #pragma unroll
                for (int m = 0; m < 4; ++m)
                    #pragma unroll
                    for (int n = 0; n < 4; ++n)
                        acc[m][n] = __builtin_amdgcn_mfma_f32_16x16x32_bf16(
                            af[m], bw[n], acc[m][n], 0, 0, 0);
            }
        } else if (isGate) {
            // kc==10: alpha (staged) x G-frags gathered from Gt (96 2B L2 loads, once)
            const char* GtB = (const char*)Gt + (size_t)b * 3 * (32 * 256 * 2);
            #pragma unroll
            for (int tap = 0; tap < 3; ++tap) {
                bf16x8 bw[4];
                #pragma unroll
                for (int n = 0; n < 4; ++n) {
                    #pragma unroll
                    for (int jj = 0; jj < 8; ++jj)
                        ((short*)&bw[n])[jj] = *(const short*)(GtB +
                            (size_t)tap * (32 * 256 * 2) +
                            (size_t)(lq * 8 + jj) * 512 +
                            (size_t)(u * 64 + n * 16 + lane15) * 2);
                }
                bf16x8 af[4];
                #pragma unroll
                for (int m = 0; m < 4; ++m) {
                    int row = m * 16 + lane15 + tap;
                    af[m] = *(const bf16x8*)(Ab + row * 64 + ((lq ^ ((row >> 1) & 3)) << 4));
                }
                #pragma unroll
                for (int m = 0; m < 4; ++m)
                    #pragma unroll
                    for (int n = 0; n < 4; ++n)
                        acc[m][n] = __builtin_amdgcn_mfma_f32_16x16x32_bf16(
                            af[m], bw[n], acc[m][n], 0, 0, 0);
            }
        }
        __syncthreads();
    }
    #undef STAGE_A

    // epilogue: sent cols 0..255, gate cols 256..511 in one LDS tile
    const int cl = t & 255, rh = t >> 8;
    const float bs = ctx_b[cl];
    const float bg = gate_b[cl];
    const int colbase = (isGate ? 256 + u * 64 : u * 64);
    float* ep = (float*)lds;
    float pm = -1e30f;
    for (int ms = 0; ms < 4; ++ms) {
        __syncthreads();
        #pragma unroll
        for (int n = 0; n < 4; ++n) {
            int col = colbase + (n << 4) + lane15;
            #pragma unroll
            for (int i2 = 0; i2 < 4; ++i2)
                ep[(lq * 4 + i2) * EP_LD + col] = acc[ms][n][i2];
        }
        __syncthreads();
        #pragma unroll
        for (int rr = 0; rr < 8; ++rr) {
            int r = rh * 8 + rr;
            float sv = ep[r * EP_LD + cl] + bs;
            float gv = ep[r * EP_LD + 256 + cl] + bg;
            pm = fmaxf(pm, tanhf(sv) * fmaxf(gv, 0.f));
        }
    }
    __syncthreads();
    ep[t] = pm;
    __syncthreads();
    if (t < 256)
        part[((size_t)b * 8 + lb) * 256 + t] = fmaxf(ep[t], ep[t + 256]);
}

// ---------------- final: max over 8 l-blocks + linear
__global__ __launch_bounds__(256) void finalize(const float* __restrict__ part,
                                                const float* __restrict__ lin_w,
                                                const float* __restrict__ lin_b,
                                                float* __restrict__ out) {
    __shared__ float pl[256];
    __shared__ float red[256];
    int b = blockIdx.x, t = threadIdx.x;
    float p = part[((size_t)b * 8) * 256 + t];
    for (int lb = 1; lb < 8; ++lb)
        p = fmaxf(p, part[((size_t)b * 8 + lb) * 256 + t]);
    pl[t] = p;
    __syncthreads();
    for (int n = 0; n < NCLASS; ++n) {
        red[t] = pl[t] * lin_w[n * NC + t];
        __syncthreads();
        for (int sft = 128; sft > 0; sft >>= 1) {
            if (t < sft) red[t] += red[t + sft];
            __syncthreads();
        }
        if (t == 0) out[b * NCLASS + n] = red[0] + lin_b[n];
        __syncthreads();
    }
}

extern "C" void kernel_launch(void* const* d_in, const int* in_sizes, int n_in,
                              void* d_out, int out_size, void* d_ws, size_t ws_size,
                              hipStream_t stream) {
    const int* cids = (const int*)d_in[0];
    const int* aids = (const int*)d_in[2];
    const float* amask = (const float*)d_in[3];
    const float* wordmat = (const float*)d_in[4];
    const float* Wm = (const float*)d_in[5];
    const float* ctx_w = (const float*)d_in[6];
    const float* ctx_b = (const float*)d_in[7];
    const float* gate_w = (const float*)d_in[8];
    const float* gate_b = (const float*)d_in[9];
    const float* lin_w = (const float*)d_in[10];
    const float* lin_b = (const float*)d_in[11];
    float* out = (float*)d_out;

    float* sbuf = (float*)d_ws;                                 // 2,097,152 f
    float* part = sbuf + 2097152;                               // 262,144 f
    __hip_bfloat16* aspb = (__hip_bfloat16*)(part + 262144);    // 1,310,720 bf16
    __hip_bfloat16* sybf = aspb + 1310720;                      // 1,310,720
    __hip_bfloat16* Wb   = sybf + 1310720;                      // 97,280
    __hip_bfloat16* Wp2  = Wb + WB_ELEMS;                       // 491,520
    __hip_bfloat16* Wg2  = Wp2 + WP2_ELEMS;                     // 245,760
    __hip_bfloat16* Gt   = Wg2 + WG2_ELEMS;                     // 3,145,728
    __hip_bfloat16* Xc   = Gt + GT_ELEMS;                       // 23,158,784

    const int prepN = WP2_ELEMS + WB_ELEMS + WG2_ELEMS + GATH_ELEMS;
    prep_all<<<(prepN + 255) / 256, 256, 0, stream>>>(ctx_w, gate_w, Wm, aids, wordmat,
                                                      Wp2, Wb, Wg2, aspb, sybf);
    xcat_x<<<BB * L1 / 8, 256, 0, stream>>>(cids, wordmat, Xc);
    asp_mfma<<<64 + BB * 3, 256, 0, stream>>>(aspb, Wb, Wg2, sybf, Gt);
    sxs_mfma<<<dim3(L1 / 64, BB), 256, 0, stream>>>(Xc, Wb, sybf, sbuf);
    softmax_col<<<dim3(BB, 4), 256, 0, stream>>>(sbuf, amask, Xc);
    conv_mfma<<<dim3(8, BB), 512, 0, stream>>>(Xc, Wp2, Gt, ctx_b, gate_b, part);
    finalize<<<BB, 256, 0, stream>>>(part, lin_w, lin_b, out);
}